// Round 8
// baseline (315.655 us; speedup 1.0000x reference)
//
#include <hip/hip_runtime.h>
#include <math.h>

// Problem constants
constexpr int Bn = 8, Cn = 128, Ln = 4096;

// Workspace layout (float offsets).
constexpr size_t OFF_O1   = 0;          // o1; later o3 (aliased)
constexpr size_t OFF_O2   = 4194304;
constexpr size_t OFF_S    = 8388608;
constexpr size_t OFF_Z    = 9437184;    // 2 dirs x 2,097,152
constexpr size_t OFF_XBCA = 13631488;   // 2 dirs x 6,291,456
constexpr size_t OFF_DTS  = 26214400;
constexpr size_t OFF_CUM  = 26279936;
constexpr size_t OFF_T    = 26345472;   // 2 dirs x 2,097,152
constexpr size_t OFF_SPREV= 30539776;   // 2 dirs x 2,097,152
constexpr size_t OFF_S2A  = 34734080;
constexpr size_t OFF_S2B  = 35782656;
constexpr size_t OFF_BN   = 36831232;
constexpr size_t OFF_O3   = 0;

constexpr long ZSTRIDE = 2097152;
constexpr long XSTRIDE = 6291456;
constexpr long TSTRIDE = 2097152;

__device__ __forceinline__ float siluf(float v) { return v / (1.0f + expf(-v)); }

// K1: o1[b,o,l] = sum_i x[b,i,l]*w[i,o] + bias[o]. 4x4 micro-tiles, 64Lx64C.
__global__ void k_lin1(const float* __restrict__ x, const float* __restrict__ w,
                       const float* __restrict__ bias, float* __restrict__ o1) {
  __shared__ float xt[128][64];
  __shared__ float wt[128][64];
  int b = blockIdx.y, l0 = blockIdx.x * 64, cb = blockIdx.z * 64;
  int tid = threadIdx.x;
  int f4 = (tid & 15) * 4, r0 = tid >> 4;
#pragma unroll
  for (int s = 0; s < 8; ++s) {
    int r = r0 + s * 16;
    *(float4*)&xt[r][f4] = *(const float4*)&x[((long)b * 128 + r) * 4096 + l0 + f4];
    *(float4*)&wt[r][f4] = *(const float4*)&w[r * 128 + cb + f4];
  }
  __syncthreads();
  int tx = tid & 15, ty = tid >> 4;
  int c0 = tx * 4, t0 = ty * 4;
  float acc[4][4];
#pragma unroll
  for (int a = 0; a < 4; ++a) {
    float bv = bias[cb + t0 + a];
#pragma unroll
    for (int q = 0; q < 4; ++q) acc[a][q] = bv;
  }
  for (int k = 0; k < 128; ++k) {
    float4 xv = *(float4*)&xt[k][c0];
    float4 wv = *(float4*)&wt[k][t0];
    float xa[4] = {xv.x, xv.y, xv.z, xv.w};
    float wa[4] = {wv.x, wv.y, wv.z, wv.w};
#pragma unroll
    for (int a = 0; a < 4; ++a)
#pragma unroll
      for (int q = 0; q < 4; ++q) acc[a][q] += wa[a] * xa[q];
  }
#pragma unroll
  for (int a = 0; a < 4; ++a)
    *(float4*)&o1[((long)b * 128 + cb + t0 + a) * 4096 + l0 + c0] =
        make_float4(acc[a][0], acc[a][1], acc[a][2], acc[a][3]);
}

// K2: depthwise 3x3 SAME + bias + silu. 4x4 patch per thread from LDS plane.
__global__ void k_dw(const float* __restrict__ o1, const float* __restrict__ wgt,
                     const float* __restrict__ bias, float* __restrict__ o2) {
  __shared__ float p[4096];
  int bc = blockIdx.x, c = bc & 127, tid = threadIdx.x;
  const float* src = o1 + (long)bc * 4096;
#pragma unroll
  for (int s4 = 0; s4 < 4; ++s4) {
    int off = s4 * 1024 + tid * 4;
    *(float4*)&p[off] = *(const float4*)&src[off];
  }
  float wr[9];
#pragma unroll
  for (int j = 0; j < 9; ++j) wr[j] = wgt[c * 9 + j];
  float bv = bias[c];
  __syncthreads();
  int wg = tid & 15, hs = tid >> 4;
  int w0 = wg * 4, h0 = hs * 4;
  float in[6][6];
#pragma unroll
  for (int ri = 0; ri < 6; ++ri) {
    int h = h0 - 1 + ri;
    if (h < 0 || h > 63) {
#pragma unroll
      for (int ci = 0; ci < 6; ++ci) in[ri][ci] = 0.f;
    } else {
      float4 cc = *(float4*)&p[h * 64 + w0];
      in[ri][1] = cc.x; in[ri][2] = cc.y; in[ri][3] = cc.z; in[ri][4] = cc.w;
      in[ri][0] = (w0 > 0) ? p[h * 64 + w0 - 1] : 0.f;
      in[ri][5] = (w0 < 60) ? p[h * 64 + w0 + 4] : 0.f;
    }
  }
#pragma unroll
  for (int r = 0; r < 4; ++r) {
    float oc[4];
#pragma unroll
    for (int q = 0; q < 4; ++q) {
      float acc = bv;
#pragma unroll
      for (int dh = 0; dh < 3; ++dh)
#pragma unroll
        for (int dq = 0; dq < 3; ++dq)
          acc += in[r + dh][q + dq] * wr[dh * 3 + dq];
      oc[q] = siluf(acc);
    }
    *(float4*)&o2[(long)bc * 4096 + (h0 + r) * 64 + w0] =
        make_float4(oc[0], oc[1], oc[2], oc[3]);
  }
}

// K3: s[b,l,d] = sum_c o2[b,c,l]*w[c,d]  (d<32). 4x2 micro-tiles.
__global__ void k_fcin(const float* __restrict__ o2, const float* __restrict__ w,
                       float* __restrict__ s) {
  __shared__ float xt[128][64];
  __shared__ float wt[128][32];
  int b = blockIdx.y, l0 = blockIdx.x * 64;
  int tid = threadIdx.x;
  int f4 = (tid & 15) * 4, r0 = tid >> 4;
#pragma unroll
  for (int st = 0; st < 8; ++st) {
    int r = r0 + st * 16;
    *(float4*)&xt[r][f4] = *(const float4*)&o2[((long)b * 128 + r) * 4096 + l0 + f4];
  }
  int f4w = (tid & 7) * 4, rw = tid >> 3;
#pragma unroll
  for (int st = 0; st < 4; ++st) {
    int r = rw + st * 32;
    *(float4*)&wt[r][f4w] = *(const float4*)&w[r * 32 + f4w];
  }
  __syncthreads();
  int tx = tid & 15, ty = tid >> 4;
  int c0 = tx * 4, d0 = ty * 2;
  float acc[2][4] = {};
  for (int k = 0; k < 128; ++k) {
    float4 xv = *(float4*)&xt[k][c0];
    float2 wv = *(float2*)&wt[k][d0];
    float xa[4] = {xv.x, xv.y, xv.z, xv.w};
#pragma unroll
    for (int q = 0; q < 4; ++q) {
      acc[0][q] += wv.x * xa[q];
      acc[1][q] += wv.y * xa[q];
    }
  }
#pragma unroll
  for (int q = 0; q < 4; ++q) {
    long ob = ((long)b * 4096 + l0 + c0 + q) * 32 + d0;
    *(float2*)&s[ob] = make_float2(acc[0][q], acc[1][q]);
  }
}

// K4: in_proj + causal conv1d + silu + dt softplus + cum, both dirs, fused.
__global__ void k_inprojconv(const float* __restrict__ s, const float* __restrict__ Win,
                             const float* __restrict__ conv_w, const float* __restrict__ conv_b,
                             const float* __restrict__ dt_bias, const float* __restrict__ A_log,
                             float* __restrict__ z, float* __restrict__ xbca,
                             float* __restrict__ dts, float* __restrict__ cum) {
  __shared__ float st[67][36];
  int dir = blockIdx.z;
  int b = blockIdx.y, l0 = blockIdx.x * 64;
  int tid = threadIdx.x;
  for (int i = tid; i < 67 * 32; i += 256) {
    int rr = i >> 5, k2 = i & 31;
    int l = l0 - 3 + rr;
    float v = 0.f;
    if (l >= 0) {
      int lsrc = dir ? (4095 - l) : l;
      v = s[((long)b * 4096 + lsrc) * 32 + k2];
    }
    st[rr][k2] = v;
  }
  __syncthreads();
  const float* W = Win + (long)dir * 32 * 257;
  float wreg[32];
#pragma unroll
  for (int k2 = 0; k2 < 32; ++k2) wreg[k2] = W[k2 * 257 + tid];
  long rowbase = (long)b * 4096 + l0;
  if (tid < 64) {
    float* zp = z + (long)dir * ZSTRIDE;
    for (int r = 0; r < 64; ++r) {
      float a = 0.f;
#pragma unroll
      for (int k2 = 0; k2 < 32; k2 += 4) {
        float4 sv = *(float4*)&st[r + 3][k2];
        a += sv.x * wreg[k2] + sv.y * wreg[k2 + 1] + sv.z * wreg[k2 + 2] + sv.w * wreg[k2 + 3];
      }
      zp[(rowbase + r) * 64 + tid] = a;
    }
    float a = 0.f;
#pragma unroll
    for (int k2 = 0; k2 < 32; ++k2) a += st[tid + 3][k2] * W[k2 * 257 + 256];
    float v = a + dt_bias[dir];
    float sp = (v > 20.f) ? v : log1pf(expf(v));
    dts[dir * 32768 + rowbase + tid] = sp;
    float cd = -expf(A_log[dir]) * sp;
#pragma unroll
    for (int off = 1; off < 64; off <<= 1) {
      float u = __shfl_up(cd, off);
      if (tid >= off) cd += u;
    }
    cum[dir * 32768 + rowbase + tid] = cd;
  } else {
    int c = tid - 64;
    float cw0 = conv_w[dir * 768 + c * 4 + 0];
    float cw1 = conv_w[dir * 768 + c * 4 + 1];
    float cw2 = conv_w[dir * 768 + c * 4 + 2];
    float cw3 = conv_w[dir * 768 + c * 4 + 3];
    float cb2 = conv_b[dir * 192 + c];
    float* xp = xbca + (long)dir * XSTRIDE;
    float win0 = 0.f, win1 = 0.f, win2 = 0.f, win3 = 0.f;
    for (int rr = 0; rr < 67; ++rr) {
      float a = 0.f;
#pragma unroll
      for (int k2 = 0; k2 < 32; k2 += 4) {
        float4 sv = *(float4*)&st[rr][k2];
        a += sv.x * wreg[k2] + sv.y * wreg[k2 + 1] + sv.z * wreg[k2 + 2] + sv.w * wreg[k2 + 3];
      }
      win0 = win1; win1 = win2; win2 = win3; win3 = a;
      if (rr >= 3) {
        float acc = cb2 + win0 * cw0 + win1 * cw1 + win2 * cw2 + win3 * cw3;
        xp[(rowbase + rr - 3) * 192 + c] = siluf(acc);
      }
    }
  }
}

// K6: chunk summary T[p][n] = sum_s f_s*X_s[p]*B_s[n].
__global__ void k_chunkT(const float* __restrict__ xbca, const float* __restrict__ dts,
                         const float* __restrict__ cum, float* __restrict__ T) {
  __shared__ float Xs[64][68], Bs[64][68];
  int dir = blockIdx.y;
  int bk = blockIdx.x, b = bk >> 6, k = bk & 63;
  int tid = threadIdx.x, lane = tid & 63, grp = tid >> 6;
  const float* xp = xbca + (long)dir * XSTRIDE;
  const float* dtp = dts + dir * 32768;
  const float* cp = cum + dir * 32768;
  long base = (long)b * 4096 + (long)k * 64;
  float clend = cp[base + 63];
  for (int r = grp; r < 64; r += 4) {
    float f = expf(clend - cp[base + r]) * dtp[base + r];
    Xs[r][lane] = xp[(base + r) * 192 + lane] * f;
    Bs[r][lane] = xp[(base + r) * 192 + 64 + lane];
  }
  __syncthreads();
  int tx = tid & 15, ty = tid >> 4;
  int p0 = ty * 4, n0 = tx * 4;
  float acc[4][4] = {};
  for (int s = 0; s < 64; ++s) {
    float4 xv = *(float4*)&Xs[s][p0];
    float4 bv = *(float4*)&Bs[s][n0];
    float xa[4] = {xv.x, xv.y, xv.z, xv.w};
    float ba[4] = {bv.x, bv.y, bv.z, bv.w};
#pragma unroll
    for (int a = 0; a < 4; ++a)
#pragma unroll
      for (int q = 0; q < 4; ++q) acc[a][q] += xa[a] * ba[q];
  }
#pragma unroll
  for (int a = 0; a < 4; ++a)
    *(float4*)&T[(long)dir * TSTRIDE + (long)bk * 4096 + (p0 + a) * 64 + n0] =
        make_float4(acc[a][0], acc[a][1], acc[a][2], acc[a][3]);
}

// K7: inter-chunk state scan (both dirs)
__global__ void k_scan(const float* __restrict__ T, const float* __restrict__ cum,
                       float* __restrict__ Sprev) {
  int idx = blockIdx.x * 256 + threadIdx.x;   // 65536
  int dir = idx >> 15, rem = idx & 32767;
  int b = rem >> 12, pn = rem & 4095;
  const float* Tp = T + (long)dir * TSTRIDE;
  float* Sp = Sprev + (long)dir * TSTRIDE;
  const float* cp = cum + dir * 32768 + b * 4096;
  float sacc = 0.f;
  for (int k = 0; k < 64; ++k) {
    long o = ((long)(b * 64 + k)) * 4096 + pn;
    Sp[o] = sacc;
    sacc = expf(cp[k * 64 + 63]) * sacc + Tp[o];
  }
}

// K8: per-chunk Y + gate + RMSNorm + out-proj, fully fused.
// STRIDED register tiling (rows ty+16a, cols tx+16b): stride-4 tiling put all
// 16-distinct-row LDS accesses on 8 banks (8-way conflicts, 5.65M cycles in r7);
// stride-16 gives bank = row+col = tx+const -> conflict-free.
__global__ void k_chunkYout(const float* __restrict__ xbca, const float* __restrict__ dts,
                            const float* __restrict__ cum, const float* __restrict__ Sprev,
                            const float* __restrict__ Dp, const float* __restrict__ z,
                            const float* __restrict__ normw, const float* __restrict__ Wout,
                            float* __restrict__ s2a, float* __restrict__ s2b) {
  __shared__ float U[64][65];   // B*dt -> Sprev
  __shared__ float V[64][65];   // C -> X -> Wn
  __shared__ float G[64][65];   // G -> gated Y
  __shared__ float cumS[64];
  __shared__ float rsc[64];
  int dir = blockIdx.y;
  int bk = blockIdx.x, b = bk >> 6, k = bk & 63;
  int tid = threadIdx.x, lane = tid & 63, grp = tid >> 6;
  const float* xp = xbca + (long)dir * XSTRIDE;
  const float* dtp = dts + dir * 32768;
  const float* cp = cum + dir * 32768;
  const float* Sp = Sprev + (long)dir * TSTRIDE;
  const float* zp = z + (long)dir * ZSTRIDE;
  long base = (long)b * 4096 + (long)k * 64;
  for (int r = grp; r < 64; r += 4) {
    float dtv = dtp[base + r];
    U[r][lane] = xp[(base + r) * 192 + 64 + lane] * dtv;   // B*dt
    V[r][lane] = xp[(base + r) * 192 + 128 + lane];        // C
  }
  if (tid < 64) cumS[tid] = cp[base + tid];
  __syncthreads();
  int tx = tid & 15, ty = tid >> 4;
  // phase a: G[t][l] = (l<=t)*exp(ct-cl)*sum_n C[t][n]*Bdt[l][n], t=ty+16a, l=tx+16b
  {
    float g[4][4] = {};
    for (int n = 0; n < 64; ++n) {
      float cv[4], uv[4];
#pragma unroll
      for (int a = 0; a < 4; ++a) cv[a] = V[ty + 16 * a][n];
#pragma unroll
      for (int bb = 0; bb < 4; ++bb) uv[bb] = U[tx + 16 * bb][n];
#pragma unroll
      for (int a = 0; a < 4; ++a)
#pragma unroll
        for (int bb = 0; bb < 4; ++bb) g[a][bb] += cv[a] * uv[bb];
    }
#pragma unroll
    for (int a = 0; a < 4; ++a) {
      int t = ty + 16 * a;
      float ct = cumS[t];
#pragma unroll
      for (int bb = 0; bb < 4; ++bb) {
        int l = tx + 16 * bb;
        G[t][l] = (l <= t) ? g[a][bb] * expf(ct - cumS[l]) : 0.f;
      }
    }
  }
  __syncthreads();
  for (int r = grp; r < 64; r += 4)
    U[r][lane] = Sp[(long)bk * 4096 + r * 64 + lane];      // Sprev[p][n]
  __syncthreads();
  // inter[t][p] = sum_n C[t][n]*Sprev[p][n]
  float inter[4][4] = {};
  for (int n = 0; n < 64; ++n) {
    float cv[4], sv[4];
#pragma unroll
    for (int a = 0; a < 4; ++a) cv[a] = V[ty + 16 * a][n];
#pragma unroll
    for (int bb = 0; bb < 4; ++bb) sv[bb] = U[tx + 16 * bb][n];
#pragma unroll
    for (int a = 0; a < 4; ++a)
#pragma unroll
      for (int bb = 0; bb < 4; ++bb) inter[a][bb] += cv[a] * sv[bb];
  }
  __syncthreads();
  for (int r = grp; r < 64; r += 4)
    V[r][lane] = xp[(base + r) * 192 + lane];              // X
  __syncthreads();
  float Dv = Dp[dir];
  float acc[4][4];
#pragma unroll
  for (int a = 0; a < 4; ++a) {
    int t = ty + 16 * a;
    float et = expf(cumS[t]);
#pragma unroll
    for (int bb = 0; bb < 4; ++bb)
      acc[a][bb] = et * inter[a][bb] + Dv * V[t][tx + 16 * bb];
  }
  for (int s = 0; s < 64; ++s) {
    float gv[4], xv[4];
#pragma unroll
    for (int a = 0; a < 4; ++a) gv[a] = G[ty + 16 * a][s];
#pragma unroll
    for (int bb = 0; bb < 4; ++bb) xv[bb] = V[s][tx + 16 * bb];
#pragma unroll
    for (int a = 0; a < 4; ++a)
#pragma unroll
      for (int bb = 0; bb < 4; ++bb) acc[a][bb] += gv[a] * xv[bb];
  }
  // ---- fused epilogue: gate (+register RMS sums), RMSNorm, out-proj ----
  __syncthreads();             // all V/G reads of this phase done
  float rowss[4] = {};
#pragma unroll
  for (int a = 0; a < 4; ++a) {
    int t = ty + 16 * a;
#pragma unroll
    for (int bb = 0; bb < 4; ++bb) {
      int p = tx + 16 * bb;
      float zv = zp[(base + t) * 64 + p];
      float yv = acc[a][bb] * siluf(zv);
      G[t][p] = yv;
      rowss[a] += yv * yv;
    }
  }
  // reduce rowss across the 16 tx-lanes (same ty) via shuffles
#pragma unroll
  for (int m = 1; m < 16; m <<= 1) {
#pragma unroll
    for (int a = 0; a < 4; ++a) rowss[a] += __shfl_xor(rowss[a], m);
  }
  if (tx == 0) {
#pragma unroll
    for (int a = 0; a < 4; ++a) rsc[ty + 16 * a] = rowss[a];
  }
  // stage Wn into V (X dead)
  for (int i = tid; i < 2048; i += 256) {
    int p = i >> 5, d = i & 31;
    V[p][d] = normw[dir * 64 + p] * Wout[(long)dir * 2048 + p * 32 + d];
  }
  __syncthreads();
  if (tid < 64) rsc[tid] = rsqrtf(rsc[tid] * (1.0f / 64.0f) + 1e-5f);
  __syncthreads();
  int tx2 = tid & 31, ty2 = tid >> 5;
  float a8[8] = {};
  for (int p = 0; p < 64; ++p) {
    float wv = V[p][tx2];
#pragma unroll
    for (int r8 = 0; r8 < 8; ++r8) a8[r8] += G[ty2 * 8 + r8][p] * wv;
  }
  float* s2x = dir ? s2b : s2a;
#pragma unroll
  for (int r8 = 0; r8 < 8; ++r8) {
    int r = ty2 * 8 + r8;
    int l = k * 64 + r;
    int lout = dir ? (4095 - l) : l;
    s2x[((long)b * 4096 + lout) * 32 + tx2] = a8[r8] * rsc[r];
  }
}

// K10: o3 = (s2a+s2b)@W — pure GEMM.
__global__ void k_fcout(const float* __restrict__ s2a, const float* __restrict__ s2b,
                        const float* __restrict__ w, float* __restrict__ o3) {
  __shared__ float st[32][68];
  __shared__ float wt[32][64];
  int b = blockIdx.y, l0 = blockIdx.x * 64, cb = blockIdx.z * 64;
  int tid = threadIdx.x;
  {
    int d = tid & 31, l = tid >> 5;
    for (int si = 0; si < 8; ++si) {
      int ll = l + si * 8;
      long o = ((long)b * 4096 + l0 + ll) * 32 + d;
      st[d][ll] = s2a[o] + s2b[o];
    }
    int f4 = (tid & 15) * 4, r = tid >> 4;
    for (int si = 0; si < 2; ++si) {
      int rr = r + si * 16;
      *(float4*)&wt[rr][f4] = *(const float4*)&w[rr * 128 + cb + f4];
    }
  }
  __syncthreads();
  int tx = tid & 15, ty = tid >> 4;
  int c0 = tx * 4, t0 = ty * 4;
  float acc[4][4] = {};
  for (int k = 0; k < 32; ++k) {
    float4 xv = *(float4*)&st[k][c0];
    float4 wv = *(float4*)&wt[k][t0];
    float xa[4] = {xv.x, xv.y, xv.z, xv.w};
    float wa[4] = {wv.x, wv.y, wv.z, wv.w};
#pragma unroll
    for (int a = 0; a < 4; ++a)
#pragma unroll
      for (int q = 0; q < 4; ++q) acc[a][q] += wa[a] * xa[q];
  }
#pragma unroll
  for (int a = 0; a < 4; ++a)
    *(float4*)&o3[((long)b * 128 + cb + t0 + a) * 4096 + l0 + c0] =
        make_float4(acc[a][0], acc[a][1], acc[a][2], acc[a][3]);
}

// K10b: per-channel sums for BatchNorm (2 atomics per block)
__global__ void k_bnstat(const float* __restrict__ o3, float* __restrict__ stats) {
  int bc = blockIdx.x;  // 1024 = (b,c)
  int tid = threadIdx.x;
  const float* p = o3 + (long)bc * 4096;
  float s = 0.f, q = 0.f;
  for (int i = tid * 4; i < 4096; i += 1024) {
    float4 v = *(const float4*)&p[i];
    s += v.x + v.y + v.z + v.w;
    q += v.x * v.x + v.y * v.y + v.z * v.z + v.w * v.w;
  }
  __shared__ float rs[4], rq[4];
  for (int off = 32; off; off >>= 1) { s += __shfl_down(s, off); q += __shfl_down(q, off); }
  if ((tid & 63) == 0) { rs[tid >> 6] = s; rq[tid >> 6] = q; }
  __syncthreads();
  if (tid == 0) {
    float a = rs[0] + rs[1] + rs[2] + rs[3];
    float b2 = rq[0] + rq[1] + rq[2] + rq[3];
    int c = bc & 127;
    atomicAdd(&stats[c], a);
    atomicAdd(&stats[128 + c], b2);
  }
}

// K12: BN + conv4 (128->128) + sigmoid + gated residual. 4x4 micro-tiles.
__global__ void k_final(const float* __restrict__ o3, const float* __restrict__ stats,
                        const float* __restrict__ bng, const float* __restrict__ bnb,
                        const float* __restrict__ w, const float* __restrict__ bias,
                        const float* __restrict__ x, float* __restrict__ out) {
  __shared__ float xt[128][64];
  __shared__ float wt[128][64];
  __shared__ float sc[128], sh[128];
  int b = blockIdx.y, l0 = blockIdx.x * 64, cb = blockIdx.z * 64;
  int tid = threadIdx.x;
  if (tid < 128) {
    float mu = stats[tid] * (1.0f / 32768.0f);
    float var = stats[128 + tid] * (1.0f / 32768.0f) - mu * mu;
    float r = rsqrtf(var + 1e-5f);
    sc[tid] = r * bng[tid];
    sh[tid] = bnb[tid] - mu * r * bng[tid];
  }
  __syncthreads();
  int f4 = (tid & 15) * 4, r0 = tid >> 4;
#pragma unroll
  for (int s = 0; s < 8; ++s) {
    int r = r0 + s * 16;
    float4 v = *(const float4*)&o3[((long)b * 128 + r) * 4096 + l0 + f4];
    float scr = sc[r], shr = sh[r];
    *(float4*)&xt[r][f4] = make_float4(fmaf(v.x, scr, shr), fmaf(v.y, scr, shr),
                                       fmaf(v.z, scr, shr), fmaf(v.w, scr, shr));
    *(float4*)&wt[r][f4] = *(const float4*)&w[r * 128 + cb + f4];
  }
  __syncthreads();
  int tx = tid & 15, ty = tid >> 4;
  int c0 = tx * 4, t0 = ty * 4;
  float acc[4][4];
#pragma unroll
  for (int a = 0; a < 4; ++a) {
    float bv = bias[cb + t0 + a];
#pragma unroll
    for (int q = 0; q < 4; ++q) acc[a][q] = bv;
  }
  for (int k = 0; k < 128; ++k) {
    float4 xv = *(float4*)&xt[k][c0];
    float4 wv = *(float4*)&wt[k][t0];
    float xa[4] = {xv.x, xv.y, xv.z, xv.w};
    float wa[4] = {wv.x, wv.y, wv.z, wv.w};
#pragma unroll
    for (int a = 0; a < 4; ++a)
#pragma unroll
      for (int q = 0; q < 4; ++q) acc[a][q] += wa[a] * xa[q];
  }
#pragma unroll
  for (int a = 0; a < 4; ++a) {
    long xi = ((long)b * 128 + cb + t0 + a) * 4096 + l0 + c0;
    float4 xv = *(const float4*)&x[xi];
    float4 o4;
    o4.x = xv.x * (1.0f + 1.0f / (1.0f + expf(-acc[a][0])));
    o4.y = xv.y * (1.0f + 1.0f / (1.0f + expf(-acc[a][1])));
    o4.z = xv.z * (1.0f + 1.0f / (1.0f + expf(-acc[a][2])));
    o4.w = xv.w * (1.0f + 1.0f / (1.0f + expf(-acc[a][3])));
    *(float4*)&out[xi] = o4;
  }
}

extern "C" void kernel_launch(void* const* d_in, const int* in_sizes, int n_in,
                              void* d_out, int out_size, void* d_ws, size_t ws_size,
                              hipStream_t stream) {
  const float* x          = (const float*)d_in[0];
  const float* lin1_w     = (const float*)d_in[1];
  const float* lin1_b     = (const float*)d_in[2];
  const float* dw_w       = (const float*)d_in[3];
  const float* dw_b       = (const float*)d_in[4];
  const float* fc_in_w    = (const float*)d_in[5];
  const float* mam_in_w   = (const float*)d_in[6];
  const float* mam_conv_w = (const float*)d_in[7];
  const float* mam_conv_b = (const float*)d_in[8];
  const float* mam_dt_bias= (const float*)d_in[9];
  const float* mam_A_log  = (const float*)d_in[10];
  const float* mam_D      = (const float*)d_in[11];
  const float* mam_norm_w = (const float*)d_in[12];
  const float* mam_out_w  = (const float*)d_in[13];
  const float* fc_out_w   = (const float*)d_in[14];
  const float* bn_g       = (const float*)d_in[15];
  const float* bn_b       = (const float*)d_in[16];
  const float* conv4_w    = (const float*)d_in[17];
  const float* conv4_b    = (const float*)d_in[18];
  float* out = (float*)d_out;
  float* ws  = (float*)d_ws;

  float* o1   = ws + OFF_O1;
  float* o2   = ws + OFF_O2;
  float* sbuf = ws + OFF_S;
  float* zbuf = ws + OFF_Z;
  float* xbca = ws + OFF_XBCA;
  float* dts  = ws + OFF_DTS;
  float* cum  = ws + OFF_CUM;
  float* Tbuf = ws + OFF_T;
  float* Sprev= ws + OFF_SPREV;
  float* s2a  = ws + OFF_S2A;
  float* s2b  = ws + OFF_S2B;
  float* bnst = ws + OFF_BN;
  float* o3   = ws + OFF_O3;

  hipMemsetAsync(bnst, 0, 256 * sizeof(float), stream);

  k_lin1<<<dim3(64, 8, 2), 256, 0, stream>>>(x, lin1_w, lin1_b, o1);
  k_dw<<<1024, 256, 0, stream>>>(o1, dw_w, dw_b, o2);
  k_fcin<<<dim3(64, 8), 256, 0, stream>>>(o2, fc_in_w, sbuf);
  k_inprojconv<<<dim3(64, 8, 2), 256, 0, stream>>>(sbuf, mam_in_w, mam_conv_w, mam_conv_b,
                                                   mam_dt_bias, mam_A_log,
                                                   zbuf, xbca, dts, cum);
  k_chunkT<<<dim3(512, 2), 256, 0, stream>>>(xbca, dts, cum, Tbuf);
  k_scan<<<256, 256, 0, stream>>>(Tbuf, cum, Sprev);
  k_chunkYout<<<dim3(512, 2), 256, 0, stream>>>(xbca, dts, cum, Sprev, mam_D, zbuf,
                                                mam_norm_w, mam_out_w, s2a, s2b);
  k_fcout<<<dim3(64, 8, 2), 256, 0, stream>>>(s2a, s2b, fc_out_w, o3);
  k_bnstat<<<1024, 256, 0, stream>>>(o3, bnst);
  k_final<<<dim3(64, 8, 2), 256, 0, stream>>>(o3, bnst, bn_g, bn_b, conv4_w, conv4_b, x, out);
}

// Round 9
// 291.621 us; speedup vs baseline: 1.0824x; 1.0824x over previous
//
#include <hip/hip_runtime.h>
#include <math.h>

// Problem constants
constexpr int Bn = 8, Cn = 128, Ln = 4096;

// Workspace layout (float offsets).
constexpr size_t OFF_O1   = 0;          // o1; later o3 (aliased)
constexpr size_t OFF_O2   = 4194304;
constexpr size_t OFF_S    = 8388608;
constexpr size_t OFF_Z    = 9437184;    // 2 dirs x 2,097,152
constexpr size_t OFF_XBCA = 13631488;   // 2 dirs x 6,291,456
constexpr size_t OFF_DTS  = 26214400;
constexpr size_t OFF_CUM  = 26279936;
constexpr size_t OFF_T    = 26345472;   // 2 dirs x 2,097,152
constexpr size_t OFF_SPREV= 30539776;   // 2 dirs x 2,097,152
constexpr size_t OFF_S2A  = 34734080;
constexpr size_t OFF_S2B  = 35782656;
constexpr size_t OFF_BN   = 36831232;
constexpr size_t OFF_O3   = 0;

constexpr long ZSTRIDE = 2097152;
constexpr long XSTRIDE = 6291456;
constexpr long TSTRIDE = 2097152;

typedef __attribute__((ext_vector_type(8))) short short8;
typedef __attribute__((ext_vector_type(4))) float f32x4;

__device__ __forceinline__ float siluf(float v) { return v / (1.0f + expf(-v)); }

__device__ __forceinline__ unsigned short tobf(float f) {
  unsigned int u = __float_as_uint(f);
  u += 0x7FFFu + ((u >> 16) & 1u);     // RNE
  return (unsigned short)(u >> 16);
}

// 8 consecutive bf16 from a stride-66 LDS row (off even) via 4 dword reads
__device__ __forceinline__ short8 ldfrag66(const unsigned short* rowp, int off) {
  union { unsigned int u[4]; short8 s; } cv;
  cv.u[0] = *(const unsigned int*)(rowp + off);
  cv.u[1] = *(const unsigned int*)(rowp + off + 2);
  cv.u[2] = *(const unsigned int*)(rowp + off + 4);
  cv.u[3] = *(const unsigned int*)(rowp + off + 6);
  return cv.s;
}

// K1: o1[b,o,l] = sum_i x[b,i,l]*w[i,o] + bias[o]. 4x4 micro-tiles, 64Lx64C.
__global__ void k_lin1(const float* __restrict__ x, const float* __restrict__ w,
                       const float* __restrict__ bias, float* __restrict__ o1) {
  __shared__ float xt[128][64];
  __shared__ float wt[128][64];
  int b = blockIdx.y, l0 = blockIdx.x * 64, cb = blockIdx.z * 64;
  int tid = threadIdx.x;
  int f4 = (tid & 15) * 4, r0 = tid >> 4;
#pragma unroll
  for (int s = 0; s < 8; ++s) {
    int r = r0 + s * 16;
    *(float4*)&xt[r][f4] = *(const float4*)&x[((long)b * 128 + r) * 4096 + l0 + f4];
    *(float4*)&wt[r][f4] = *(const float4*)&w[r * 128 + cb + f4];
  }
  __syncthreads();
  int tx = tid & 15, ty = tid >> 4;
  int c0 = tx * 4, t0 = ty * 4;
  float acc[4][4];
#pragma unroll
  for (int a = 0; a < 4; ++a) {
    float bv = bias[cb + t0 + a];
#pragma unroll
    for (int q = 0; q < 4; ++q) acc[a][q] = bv;
  }
  for (int k = 0; k < 128; ++k) {
    float4 xv = *(float4*)&xt[k][c0];
    float4 wv = *(float4*)&wt[k][t0];
    float xa[4] = {xv.x, xv.y, xv.z, xv.w};
    float wa[4] = {wv.x, wv.y, wv.z, wv.w};
#pragma unroll
    for (int a = 0; a < 4; ++a)
#pragma unroll
      for (int q = 0; q < 4; ++q) acc[a][q] += wa[a] * xa[q];
  }
#pragma unroll
  for (int a = 0; a < 4; ++a)
    *(float4*)&o1[((long)b * 128 + cb + t0 + a) * 4096 + l0 + c0] =
        make_float4(acc[a][0], acc[a][1], acc[a][2], acc[a][3]);
}

// K2: depthwise 3x3 SAME + bias + silu. 4x4 patch per thread from LDS plane.
__global__ void k_dw(const float* __restrict__ o1, const float* __restrict__ wgt,
                     const float* __restrict__ bias, float* __restrict__ o2) {
  __shared__ float p[4096];
  int bc = blockIdx.x, c = bc & 127, tid = threadIdx.x;
  const float* src = o1 + (long)bc * 4096;
#pragma unroll
  for (int s4 = 0; s4 < 4; ++s4) {
    int off = s4 * 1024 + tid * 4;
    *(float4*)&p[off] = *(const float4*)&src[off];
  }
  float wr[9];
#pragma unroll
  for (int j = 0; j < 9; ++j) wr[j] = wgt[c * 9 + j];
  float bv = bias[c];
  __syncthreads();
  int wg = tid & 15, hs = tid >> 4;
  int w0 = wg * 4, h0 = hs * 4;
  float in[6][6];
#pragma unroll
  for (int ri = 0; ri < 6; ++ri) {
    int h = h0 - 1 + ri;
    if (h < 0 || h > 63) {
#pragma unroll
      for (int ci = 0; ci < 6; ++ci) in[ri][ci] = 0.f;
    } else {
      float4 cc = *(float4*)&p[h * 64 + w0];
      in[ri][1] = cc.x; in[ri][2] = cc.y; in[ri][3] = cc.z; in[ri][4] = cc.w;
      in[ri][0] = (w0 > 0) ? p[h * 64 + w0 - 1] : 0.f;
      in[ri][5] = (w0 < 60) ? p[h * 64 + w0 + 4] : 0.f;
    }
  }
#pragma unroll
  for (int r = 0; r < 4; ++r) {
    float oc[4];
#pragma unroll
    for (int q = 0; q < 4; ++q) {
      float acc = bv;
#pragma unroll
      for (int dh = 0; dh < 3; ++dh)
#pragma unroll
        for (int dq = 0; dq < 3; ++dq)
          acc += in[r + dh][q + dq] * wr[dh * 3 + dq];
      oc[q] = siluf(acc);
    }
    *(float4*)&o2[(long)bc * 4096 + (h0 + r) * 64 + w0] =
        make_float4(oc[0], oc[1], oc[2], oc[3]);
  }
}

// K3: s[b,l,d] = sum_c o2[b,c,l]*w[c,d]  (d<32). 4x2 micro-tiles.
__global__ void k_fcin(const float* __restrict__ o2, const float* __restrict__ w,
                       float* __restrict__ s) {
  __shared__ float xt[128][64];
  __shared__ float wt[128][32];
  int b = blockIdx.y, l0 = blockIdx.x * 64;
  int tid = threadIdx.x;
  int f4 = (tid & 15) * 4, r0 = tid >> 4;
#pragma unroll
  for (int st = 0; st < 8; ++st) {
    int r = r0 + st * 16;
    *(float4*)&xt[r][f4] = *(const float4*)&o2[((long)b * 128 + r) * 4096 + l0 + f4];
  }
  int f4w = (tid & 7) * 4, rw = tid >> 3;
#pragma unroll
  for (int st = 0; st < 4; ++st) {
    int r = rw + st * 32;
    *(float4*)&wt[r][f4w] = *(const float4*)&w[r * 32 + f4w];
  }
  __syncthreads();
  int tx = tid & 15, ty = tid >> 4;
  int c0 = tx * 4, d0 = ty * 2;
  float acc[2][4] = {};
  for (int k = 0; k < 128; ++k) {
    float4 xv = *(float4*)&xt[k][c0];
    float2 wv = *(float2*)&wt[k][d0];
    float xa[4] = {xv.x, xv.y, xv.z, xv.w};
#pragma unroll
    for (int q = 0; q < 4; ++q) {
      acc[0][q] += wv.x * xa[q];
      acc[1][q] += wv.y * xa[q];
    }
  }
#pragma unroll
  for (int q = 0; q < 4; ++q) {
    long ob = ((long)b * 4096 + l0 + c0 + q) * 32 + d0;
    *(float2*)&s[ob] = make_float2(acc[0][q], acc[1][q]);
  }
}

// K4: in_proj + causal conv1d + silu + dt softplus + cum, both dirs, fused.
__global__ void k_inprojconv(const float* __restrict__ s, const float* __restrict__ Win,
                             const float* __restrict__ conv_w, const float* __restrict__ conv_b,
                             const float* __restrict__ dt_bias, const float* __restrict__ A_log,
                             float* __restrict__ z, float* __restrict__ xbca,
                             float* __restrict__ dts, float* __restrict__ cum) {
  __shared__ float st[67][36];
  int dir = blockIdx.z;
  int b = blockIdx.y, l0 = blockIdx.x * 64;
  int tid = threadIdx.x;
  for (int i = tid; i < 67 * 32; i += 256) {
    int rr = i >> 5, k2 = i & 31;
    int l = l0 - 3 + rr;
    float v = 0.f;
    if (l >= 0) {
      int lsrc = dir ? (4095 - l) : l;
      v = s[((long)b * 4096 + lsrc) * 32 + k2];
    }
    st[rr][k2] = v;
  }
  __syncthreads();
  const float* W = Win + (long)dir * 32 * 257;
  float wreg[32];
#pragma unroll
  for (int k2 = 0; k2 < 32; ++k2) wreg[k2] = W[k2 * 257 + tid];
  long rowbase = (long)b * 4096 + l0;
  if (tid < 64) {
    float* zp = z + (long)dir * ZSTRIDE;
    for (int r = 0; r < 64; ++r) {
      float a = 0.f;
#pragma unroll
      for (int k2 = 0; k2 < 32; k2 += 4) {
        float4 sv = *(float4*)&st[r + 3][k2];
        a += sv.x * wreg[k2] + sv.y * wreg[k2 + 1] + sv.z * wreg[k2 + 2] + sv.w * wreg[k2 + 3];
      }
      zp[(rowbase + r) * 64 + tid] = a;
    }
    float a = 0.f;
#pragma unroll
    for (int k2 = 0; k2 < 32; ++k2) a += st[tid + 3][k2] * W[k2 * 257 + 256];
    float v = a + dt_bias[dir];
    float sp = (v > 20.f) ? v : log1pf(expf(v));
    dts[dir * 32768 + rowbase + tid] = sp;
    float cd = -expf(A_log[dir]) * sp;
#pragma unroll
    for (int off = 1; off < 64; off <<= 1) {
      float u = __shfl_up(cd, off);
      if (tid >= off) cd += u;
    }
    cum[dir * 32768 + rowbase + tid] = cd;
  } else {
    int c = tid - 64;
    float cw0 = conv_w[dir * 768 + c * 4 + 0];
    float cw1 = conv_w[dir * 768 + c * 4 + 1];
    float cw2 = conv_w[dir * 768 + c * 4 + 2];
    float cw3 = conv_w[dir * 768 + c * 4 + 3];
    float cb2 = conv_b[dir * 192 + c];
    float* xp = xbca + (long)dir * XSTRIDE;
    float win0 = 0.f, win1 = 0.f, win2 = 0.f, win3 = 0.f;
    for (int rr = 0; rr < 67; ++rr) {
      float a = 0.f;
#pragma unroll
      for (int k2 = 0; k2 < 32; k2 += 4) {
        float4 sv = *(float4*)&st[rr][k2];
        a += sv.x * wreg[k2] + sv.y * wreg[k2 + 1] + sv.z * wreg[k2 + 2] + sv.w * wreg[k2 + 3];
      }
      win0 = win1; win1 = win2; win2 = win3; win3 = a;
      if (rr >= 3) {
        float acc = cb2 + win0 * cw0 + win1 * cw1 + win2 * cw2 + win3 * cw3;
        xp[(rowbase + rr - 3) * 192 + c] = siluf(acc);
      }
    }
  }
}

// K6: chunk summary T[p][n] = sum_s f_s*X_s[p]*B_s[n].
__global__ void k_chunkT(const float* __restrict__ xbca, const float* __restrict__ dts,
                         const float* __restrict__ cum, float* __restrict__ T) {
  __shared__ float Xs[64][68], Bs[64][68];
  int dir = blockIdx.y;
  int bk = blockIdx.x, b = bk >> 6, k = bk & 63;
  int tid = threadIdx.x, lane = tid & 63, grp = tid >> 6;
  const float* xp = xbca + (long)dir * XSTRIDE;
  const float* dtp = dts + dir * 32768;
  const float* cp = cum + dir * 32768;
  long base = (long)b * 4096 + (long)k * 64;
  float clend = cp[base + 63];
  for (int r = grp; r < 64; r += 4) {
    float f = expf(clend - cp[base + r]) * dtp[base + r];
    Xs[r][lane] = xp[(base + r) * 192 + lane] * f;
    Bs[r][lane] = xp[(base + r) * 192 + 64 + lane];
  }
  __syncthreads();
  int tx = tid & 15, ty = tid >> 4;
  int p0 = ty * 4, n0 = tx * 4;
  float acc[4][4] = {};
  for (int s = 0; s < 64; ++s) {
    float4 xv = *(float4*)&Xs[s][p0];
    float4 bv = *(float4*)&Bs[s][n0];
    float xa[4] = {xv.x, xv.y, xv.z, xv.w};
    float ba[4] = {bv.x, bv.y, bv.z, bv.w};
#pragma unroll
    for (int a = 0; a < 4; ++a)
#pragma unroll
      for (int q = 0; q < 4; ++q) acc[a][q] += xa[a] * ba[q];
  }
#pragma unroll
  for (int a = 0; a < 4; ++a)
    *(float4*)&T[(long)dir * TSTRIDE + (long)bk * 4096 + (p0 + a) * 64 + n0] =
        make_float4(acc[a][0], acc[a][1], acc[a][2], acc[a][3]);
}

// K7: inter-chunk state scan (both dirs)
__global__ void k_scan(const float* __restrict__ T, const float* __restrict__ cum,
                       float* __restrict__ Sprev) {
  int idx = blockIdx.x * 256 + threadIdx.x;   // 65536
  int dir = idx >> 15, rem = idx & 32767;
  int b = rem >> 12, pn = rem & 4095;
  const float* Tp = T + (long)dir * TSTRIDE;
  float* Sp = Sprev + (long)dir * TSTRIDE;
  const float* cp = cum + dir * 32768 + b * 4096;
  float sacc = 0.f;
  for (int k = 0; k < 64; ++k) {
    long o = ((long)(b * 64 + k)) * 4096 + pn;
    Sp[o] = sacc;
    sacc = expf(cp[k * 64 + 63]) * sacc + Tp[o];
  }
}

// K8: per-chunk Y + gate + RMSNorm + out-proj — MFMA bf16 version.
// r8 post-mortem: VALU version was LDS-instruction-pipe bound (~2100 ds_read_b32
// per wave). MFMA cuts that ~10x. Layouts (m89/m120): C/D col=lane&15,
// row=quad*4+reg; A/B frag [idx=lane&15][k=quad*8+j]. Stride-66 rows make
// transposed X staging conflict-free (odd dword stride); wave mt owns G rows
// mt*16..mt*16+15 in every phase (wave-private).
__global__ __launch_bounds__(256) void k_chunkYout(
    const float* __restrict__ xbca, const float* __restrict__ dts,
    const float* __restrict__ cum, const float* __restrict__ Sprev,
    const float* __restrict__ Dp, const float* __restrict__ z,
    const float* __restrict__ normw, const float* __restrict__ Wout,
    float* __restrict__ s2a, float* __restrict__ s2b) {
  __shared__ unsigned short Cb[64][72];    // C[t][n]   (b128 frags)
  __shared__ unsigned short Bop[64][66];   // Bdt -> Sprev -> X^T (b32 frags)
  __shared__ unsigned short Gb[64][72];    // G[t][s] -> Yn[t][p] (b128 frags)
  __shared__ unsigned short WnT[32][66];   // Wn^T[d][p]
  __shared__ float cumS[64];
  int dir = blockIdx.y;
  int bk = blockIdx.x, b = bk >> 6, k = bk & 63;
  int tid = threadIdx.x, lane = tid & 63, mt = tid >> 6;
  int q = lane >> 4, i = lane & 15;
  const float* xp = xbca + (long)dir * XSTRIDE;
  const float* dtp = dts + dir * 32768;
  const float* cp = cum + dir * 32768;
  const float* Sp = Sprev + (long)dir * TSTRIDE;
  const float* zp = z + (long)dir * ZSTRIDE;
  long base = (long)b * 4096 + (long)k * 64;

  // stage C (bf16), B*dt (bf16), Wn^T (bf16), cum
  for (int r = mt; r < 64; r += 4) {
    float dtv = dtp[base + r];
    Cb[r][lane]  = tobf(xp[(base + r) * 192 + 128 + lane]);
    Bop[r][lane] = tobf(xp[(base + r) * 192 + 64 + lane] * dtv);
  }
  for (int idx = tid; idx < 2048; idx += 256) {
    int p = idx >> 5, d = idx & 31;
    WnT[d][p] = tobf(normw[dir * 64 + p] * Wout[(long)dir * 2048 + p * 32 + d]);
  }
  if (tid < 64) cumS[tid] = cp[base + tid];
  __syncthreads();

  // A-frags for C rows mt*16+i (used in phases a and b)
  short8 a0 = *(const short8*)&Cb[mt * 16 + i][q * 8];
  short8 a1 = *(const short8*)&Cb[mt * 16 + i][q * 8 + 32];

  // phase a: G[t][l] = (l<=t)*exp(ct-cl)*sum_n C[t][n]*Bdt[l][n]
#pragma unroll
  for (int lt = 0; lt < 4; ++lt) {
    short8 b0 = ldfrag66(&Bop[lt * 16 + i][0], q * 8);
    short8 b1 = ldfrag66(&Bop[lt * 16 + i][0], q * 8 + 32);
    f32x4 d = {0.f, 0.f, 0.f, 0.f};
    d = __builtin_amdgcn_mfma_f32_16x16x32_bf16(a0, b0, d, 0, 0, 0);
    d = __builtin_amdgcn_mfma_f32_16x16x32_bf16(a1, b1, d, 0, 0, 0);
#pragma unroll
    for (int r2 = 0; r2 < 4; ++r2) {
      int t = mt * 16 + q * 4 + r2;
      int l = lt * 16 + i;
      float g = (l <= t) ? d[r2] * expf(cumS[t] - cumS[l]) : 0.f;
      Gb[t][l] = tobf(g);
    }
  }
  __syncthreads();

  // stage Sprev[p][n] into Bop
  for (int r = mt; r < 64; r += 4)
    Bop[r][lane] = tobf(Sp[(long)bk * 4096 + r * 64 + lane]);
  __syncthreads();

  // phase b: inter[t][p] = sum_n C[t][n]*Sprev[p][n]  (kept in registers)
  f32x4 dint[4];
#pragma unroll
  for (int lt = 0; lt < 4; ++lt) {
    short8 b0 = ldfrag66(&Bop[lt * 16 + i][0], q * 8);
    short8 b1 = ldfrag66(&Bop[lt * 16 + i][0], q * 8 + 32);
    f32x4 d = {0.f, 0.f, 0.f, 0.f};
    d = __builtin_amdgcn_mfma_f32_16x16x32_bf16(a0, b0, d, 0, 0, 0);
    d = __builtin_amdgcn_mfma_f32_16x16x32_bf16(a1, b1, d, 0, 0, 0);
    dint[lt] = d;
  }
  __syncthreads();

  // stage X^T[p][s] into Bop (wave mt covers s in [mt*16, mt*16+16))
#pragma unroll
  for (int j = 0; j < 8; ++j) {
    int s = mt * 16 + 2 * j;
    float x0 = xp[(base + s) * 192 + lane];
    float x1 = xp[(base + s + 1) * 192 + lane];
    unsigned int pk = (unsigned int)tobf(x0) | ((unsigned int)tobf(x1) << 16);
    *(unsigned int*)&Bop[lane][s] = pk;
  }
  __syncthreads();

  // phase d: Y = G·X + exp(ct)*inter + D*X, then gate + RMS (registers)
  short8 g0 = *(const short8*)&Gb[mt * 16 + i][q * 8];
  short8 g1 = *(const short8*)&Gb[mt * 16 + i][q * 8 + 32];
  float Dv = Dp[dir];
  float yv[4][4];
  float rowss[4] = {0.f, 0.f, 0.f, 0.f};
#pragma unroll
  for (int lt = 0; lt < 4; ++lt) {
    short8 b0 = ldfrag66(&Bop[lt * 16 + i][0], q * 8);
    short8 b1 = ldfrag66(&Bop[lt * 16 + i][0], q * 8 + 32);
    f32x4 d = {0.f, 0.f, 0.f, 0.f};
    d = __builtin_amdgcn_mfma_f32_16x16x32_bf16(g0, b0, d, 0, 0, 0);
    d = __builtin_amdgcn_mfma_f32_16x16x32_bf16(g1, b1, d, 0, 0, 0);
#pragma unroll
    for (int r2 = 0; r2 < 4; ++r2) {
      int t = mt * 16 + q * 4 + r2;
      int p = lt * 16 + i;
      float et = expf(cumS[t]);
      float xv = xp[(base + t) * 192 + p];     // fp32 skip term
      float y = d[r2] + et * dint[lt][r2] + Dv * xv;
      float zv = zp[(base + t) * 64 + p];
      float v = y * siluf(zv);
      yv[lt][r2] = v;
      rowss[r2] += v * v;
    }
  }
#pragma unroll
  for (int m = 1; m < 16; m <<= 1) {
#pragma unroll
    for (int r2 = 0; r2 < 4; ++r2) rowss[r2] += __shfl_xor(rowss[r2], m);
  }
  float rscv[4];
#pragma unroll
  for (int r2 = 0; r2 < 4; ++r2)
    rscv[r2] = rsqrtf(rowss[r2] * (1.0f / 64.0f) + 1e-5f);
  // write normalized gated Y back to Gb (wave-private rows)
#pragma unroll
  for (int lt = 0; lt < 4; ++lt)
#pragma unroll
    for (int r2 = 0; r2 < 4; ++r2) {
      int t = mt * 16 + q * 4 + r2;
      int p = lt * 16 + i;
      Gb[t][p] = tobf(yv[lt][r2] * rscv[r2]);
    }
  __syncthreads();

  // out-proj: s2[l][d] = sum_p Yn[l][p]*Wn[p][d]
  short8 y0 = *(const short8*)&Gb[mt * 16 + i][q * 8];
  short8 y1 = *(const short8*)&Gb[mt * 16 + i][q * 8 + 32];
  float* s2x = dir ? s2b : s2a;
#pragma unroll
  for (int dt = 0; dt < 2; ++dt) {
    short8 b0 = ldfrag66(&WnT[dt * 16 + i][0], q * 8);
    short8 b1 = ldfrag66(&WnT[dt * 16 + i][0], q * 8 + 32);
    f32x4 d = {0.f, 0.f, 0.f, 0.f};
    d = __builtin_amdgcn_mfma_f32_16x16x32_bf16(y0, b0, d, 0, 0, 0);
    d = __builtin_amdgcn_mfma_f32_16x16x32_bf16(y1, b1, d, 0, 0, 0);
#pragma unroll
    for (int r2 = 0; r2 < 4; ++r2) {
      int tl = mt * 16 + q * 4 + r2;
      int l = k * 64 + tl;
      int lout = dir ? (4095 - l) : l;
      int dd = dt * 16 + i;
      s2x[((long)b * 4096 + lout) * 32 + dd] = d[r2];
    }
  }
}

// K10: o3 = (s2a+s2b)@W — pure GEMM.
__global__ void k_fcout(const float* __restrict__ s2a, const float* __restrict__ s2b,
                        const float* __restrict__ w, float* __restrict__ o3) {
  __shared__ float st[32][68];
  __shared__ float wt[32][64];
  int b = blockIdx.y, l0 = blockIdx.x * 64, cb = blockIdx.z * 64;
  int tid = threadIdx.x;
  {
    int d = tid & 31, l = tid >> 5;
    for (int si = 0; si < 8; ++si) {
      int ll = l + si * 8;
      long o = ((long)b * 4096 + l0 + ll) * 32 + d;
      st[d][ll] = s2a[o] + s2b[o];
    }
    int f4 = (tid & 15) * 4, r = tid >> 4;
    for (int si = 0; si < 2; ++si) {
      int rr = r + si * 16;
      *(float4*)&wt[rr][f4] = *(const float4*)&w[rr * 128 + cb + f4];
    }
  }
  __syncthreads();
  int tx = tid & 15, ty = tid >> 4;
  int c0 = tx * 4, t0 = ty * 4;
  float acc[4][4] = {};
  for (int k = 0; k < 32; ++k) {
    float4 xv = *(float4*)&st[k][c0];
    float4 wv = *(float4*)&wt[k][t0];
    float xa[4] = {xv.x, xv.y, xv.z, xv.w};
    float wa[4] = {wv.x, wv.y, wv.z, wv.w};
#pragma unroll
    for (int a = 0; a < 4; ++a)
#pragma unroll
      for (int q = 0; q < 4; ++q) acc[a][q] += wa[a] * xa[q];
  }
#pragma unroll
  for (int a = 0; a < 4; ++a)
    *(float4*)&o3[((long)b * 128 + cb + t0 + a) * 4096 + l0 + c0] =
        make_float4(acc[a][0], acc[a][1], acc[a][2], acc[a][3]);
}

// K10b: per-channel sums for BatchNorm (2 atomics per block)
__global__ void k_bnstat(const float* __restrict__ o3, float* __restrict__ stats) {
  int bc = blockIdx.x;  // 1024 = (b,c)
  int tid = threadIdx.x;
  const float* p = o3 + (long)bc * 4096;
  float s = 0.f, q = 0.f;
  for (int i = tid * 4; i < 4096; i += 1024) {
    float4 v = *(const float4*)&p[i];
    s += v.x + v.y + v.z + v.w;
    q += v.x * v.x + v.y * v.y + v.z * v.z + v.w * v.w;
  }
  __shared__ float rs[4], rq[4];
  for (int off = 32; off; off >>= 1) { s += __shfl_down(s, off); q += __shfl_down(q, off); }
  if ((tid & 63) == 0) { rs[tid >> 6] = s; rq[tid >> 6] = q; }
  __syncthreads();
  if (tid == 0) {
    float a = rs[0] + rs[1] + rs[2] + rs[3];
    float b2 = rq[0] + rq[1] + rq[2] + rq[3];
    int c = bc & 127;
    atomicAdd(&stats[c], a);
    atomicAdd(&stats[128 + c], b2);
  }
}

// K12: BN + conv4 (128->128) + sigmoid + gated residual. 4x4 micro-tiles.
__global__ void k_final(const float* __restrict__ o3, const float* __restrict__ stats,
                        const float* __restrict__ bng, const float* __restrict__ bnb,
                        const float* __restrict__ w, const float* __restrict__ bias,
                        const float* __restrict__ x, float* __restrict__ out) {
  __shared__ float xt[128][64];
  __shared__ float wt[128][64];
  __shared__ float sc[128], sh[128];
  int b = blockIdx.y, l0 = blockIdx.x * 64, cb = blockIdx.z * 64;
  int tid = threadIdx.x;
  if (tid < 128) {
    float mu = stats[tid] * (1.0f / 32768.0f);
    float var = stats[128 + tid] * (1.0f / 32768.0f) - mu * mu;
    float r = rsqrtf(var + 1e-5f);
    sc[tid] = r * bng[tid];
    sh[tid] = bnb[tid] - mu * r * bng[tid];
  }
  __syncthreads();
  int f4 = (tid & 15) * 4, r0 = tid >> 4;
#pragma unroll
  for (int s = 0; s < 8; ++s) {
    int r = r0 + s * 16;
    float4 v = *(const float4*)&o3[((long)b * 128 + r) * 4096 + l0 + f4];
    float scr = sc[r], shr = sh[r];
    *(float4*)&xt[r][f4] = make_float4(fmaf(v.x, scr, shr), fmaf(v.y, scr, shr),
                                       fmaf(v.z, scr, shr), fmaf(v.w, scr, shr));
    *(float4*)&wt[r][f4] = *(const float4*)&w[r * 128 + cb + f4];
  }
  __syncthreads();
  int tx = tid & 15, ty = tid >> 4;
  int c0 = tx * 4, t0 = ty * 4;
  float acc[4][4];
#pragma unroll
  for (int a = 0; a < 4; ++a) {
    float bv = bias[cb + t0 + a];
#pragma unroll
    for (int q = 0; q < 4; ++q) acc[a][q] = bv;
  }
  for (int k = 0; k < 128; ++k) {
    float4 xv = *(float4*)&xt[k][c0];
    float4 wv = *(float4*)&wt[k][t0];
    float xa[4] = {xv.x, xv.y, xv.z, xv.w};
    float wa[4] = {wv.x, wv.y, wv.z, wv.w};
#pragma unroll
    for (int a = 0; a < 4; ++a)
#pragma unroll
      for (int q = 0; q < 4; ++q) acc[a][q] += wa[a] * xa[q];
  }
#pragma unroll
  for (int a = 0; a < 4; ++a) {
    long xi = ((long)b * 128 + cb + t0 + a) * 4096 + l0 + c0;
    float4 xv = *(const float4*)&x[xi];
    float4 o4;
    o4.x = xv.x * (1.0f + 1.0f / (1.0f + expf(-acc[a][0])));
    o4.y = xv.y * (1.0f + 1.0f / (1.0f + expf(-acc[a][1])));
    o4.z = xv.z * (1.0f + 1.0f / (1.0f + expf(-acc[a][2])));
    o4.w = xv.w * (1.0f + 1.0f / (1.0f + expf(-acc[a][3])));
    *(float4*)&out[xi] = o4;
  }
}

extern "C" void kernel_launch(void* const* d_in, const int* in_sizes, int n_in,
                              void* d_out, int out_size, void* d_ws, size_t ws_size,
                              hipStream_t stream) {
  const float* x          = (const float*)d_in[0];
  const float* lin1_w     = (const float*)d_in[1];
  const float* lin1_b     = (const float*)d_in[2];
  const float* dw_w       = (const float*)d_in[3];
  const float* dw_b       = (const float*)d_in[4];
  const float* fc_in_w    = (const float*)d_in[5];
  const float* mam_in_w   = (const float*)d_in[6];
  const float* mam_conv_w = (const float*)d_in[7];
  const float* mam_conv_b = (const float*)d_in[8];
  const float* mam_dt_bias= (const float*)d_in[9];
  const float* mam_A_log  = (const float*)d_in[10];
  const float* mam_D      = (const float*)d_in[11];
  const float* mam_norm_w = (const float*)d_in[12];
  const float* mam_out_w  = (const float*)d_in[13];
  const float* fc_out_w   = (const float*)d_in[14];
  const float* bn_g       = (const float*)d_in[15];
  const float* bn_b       = (const float*)d_in[16];
  const float* conv4_w    = (const float*)d_in[17];
  const float* conv4_b    = (const float*)d_in[18];
  float* out = (float*)d_out;
  float* ws  = (float*)d_ws;

  float* o1   = ws + OFF_O1;
  float* o2   = ws + OFF_O2;
  float* sbuf = ws + OFF_S;
  float* zbuf = ws + OFF_Z;
  float* xbca = ws + OFF_XBCA;
  float* dts  = ws + OFF_DTS;
  float* cum  = ws + OFF_CUM;
  float* Tbuf = ws + OFF_T;
  float* Sprev= ws + OFF_SPREV;
  float* s2a  = ws + OFF_S2A;
  float* s2b  = ws + OFF_S2B;
  float* bnst = ws + OFF_BN;
  float* o3   = ws + OFF_O3;

  hipMemsetAsync(bnst, 0, 256 * sizeof(float), stream);

  k_lin1<<<dim3(64, 8, 2), 256, 0, stream>>>(x, lin1_w, lin1_b, o1);
  k_dw<<<1024, 256, 0, stream>>>(o1, dw_w, dw_b, o2);
  k_fcin<<<dim3(64, 8), 256, 0, stream>>>(o2, fc_in_w, sbuf);
  k_inprojconv<<<dim3(64, 8, 2), 256, 0, stream>>>(sbuf, mam_in_w, mam_conv_w, mam_conv_b,
                                                   mam_dt_bias, mam_A_log,
                                                   zbuf, xbca, dts, cum);
  k_chunkT<<<dim3(512, 2), 256, 0, stream>>>(xbca, dts, cum, Tbuf);
  k_scan<<<256, 256, 0, stream>>>(Tbuf, cum, Sprev);
  k_chunkYout<<<dim3(512, 2), 256, 0, stream>>>(xbca, dts, cum, Sprev, mam_D, zbuf,
                                                mam_norm_w, mam_out_w, s2a, s2b);
  k_fcout<<<dim3(64, 8, 2), 256, 0, stream>>>(s2a, s2b, fc_out_w, o3);
  k_bnstat<<<1024, 256, 0, stream>>>(o3, bnst);
  k_final<<<dim3(64, 8, 2), 256, 0, stream>>>(o3, bnst, bn_g, bn_b, conv4_w, conv4_b, x, out);
}

// Round 10
// 275.769 us; speedup vs baseline: 1.1446x; 1.0575x over previous
//
#include <hip/hip_runtime.h>
#include <math.h>

// Problem constants
constexpr int Bn = 8, Cn = 128, Ln = 4096;

// Workspace layout (float offsets).
constexpr size_t OFF_O1   = 0;          // o1; later o3 (aliased)
constexpr size_t OFF_O2   = 4194304;
constexpr size_t OFF_S    = 8388608;
constexpr size_t OFF_Z    = 9437184;    // 2 dirs x 2,097,152
constexpr size_t OFF_XBCA = 13631488;   // 2 dirs x 6,291,456
constexpr size_t OFF_DTS  = 26214400;
constexpr size_t OFF_CUM  = 26279936;
constexpr size_t OFF_T    = 26345472;   // 2 dirs x 2,097,152
constexpr size_t OFF_SPREV= 30539776;   // 2 dirs x 2,097,152
constexpr size_t OFF_S2A  = 34734080;
constexpr size_t OFF_S2B  = 35782656;
constexpr size_t OFF_BN   = 36831232;
constexpr size_t OFF_O3   = 0;

constexpr long ZSTRIDE = 2097152;
constexpr long XSTRIDE = 6291456;
constexpr long TSTRIDE = 2097152;

typedef __attribute__((ext_vector_type(8))) short short8;
typedef __attribute__((ext_vector_type(4))) float f32x4;

__device__ __forceinline__ float siluf(float v) { return v / (1.0f + expf(-v)); }

__device__ __forceinline__ unsigned short tobf(float f) {
  unsigned int u = __float_as_uint(f);
  u += 0x7FFFu + ((u >> 16) & 1u);     // RNE
  return (unsigned short)(u >> 16);
}

__device__ __forceinline__ float frombf(unsigned short u) {
  return __uint_as_float(((unsigned int)u) << 16);
}

// 8 consecutive bf16 from a stride-66 LDS row (off even) via 4 dword reads
__device__ __forceinline__ short8 ldfrag66(const unsigned short* rowp, int off) {
  union { unsigned int u[4]; short8 s; } cv;
  cv.u[0] = *(const unsigned int*)(rowp + off);
  cv.u[1] = *(const unsigned int*)(rowp + off + 2);
  cv.u[2] = *(const unsigned int*)(rowp + off + 4);
  cv.u[3] = *(const unsigned int*)(rowp + off + 6);
  return cv.s;
}

// K1: o1[b,o,l] = sum_i x[b,i,l]*w[i,o] + bias[o]. 4x4 micro-tiles, 64Lx64C.
__global__ void k_lin1(const float* __restrict__ x, const float* __restrict__ w,
                       const float* __restrict__ bias, float* __restrict__ o1) {
  __shared__ float xt[128][64];
  __shared__ float wt[128][64];
  int b = blockIdx.y, l0 = blockIdx.x * 64, cb = blockIdx.z * 64;
  int tid = threadIdx.x;
  int f4 = (tid & 15) * 4, r0 = tid >> 4;
#pragma unroll
  for (int s = 0; s < 8; ++s) {
    int r = r0 + s * 16;
    *(float4*)&xt[r][f4] = *(const float4*)&x[((long)b * 128 + r) * 4096 + l0 + f4];
    *(float4*)&wt[r][f4] = *(const float4*)&w[r * 128 + cb + f4];
  }
  __syncthreads();
  int tx = tid & 15, ty = tid >> 4;
  int c0 = tx * 4, t0 = ty * 4;
  float acc[4][4];
#pragma unroll
  for (int a = 0; a < 4; ++a) {
    float bv = bias[cb + t0 + a];
#pragma unroll
    for (int q = 0; q < 4; ++q) acc[a][q] = bv;
  }
  for (int k = 0; k < 128; ++k) {
    float4 xv = *(float4*)&xt[k][c0];
    float4 wv = *(float4*)&wt[k][t0];
    float xa[4] = {xv.x, xv.y, xv.z, xv.w};
    float wa[4] = {wv.x, wv.y, wv.z, wv.w};
#pragma unroll
    for (int a = 0; a < 4; ++a)
#pragma unroll
      for (int q = 0; q < 4; ++q) acc[a][q] += wa[a] * xa[q];
  }
#pragma unroll
  for (int a = 0; a < 4; ++a)
    *(float4*)&o1[((long)b * 128 + cb + t0 + a) * 4096 + l0 + c0] =
        make_float4(acc[a][0], acc[a][1], acc[a][2], acc[a][3]);
}

// K2: depthwise 3x3 SAME + bias + silu. 4x4 patch per thread from LDS plane.
__global__ void k_dw(const float* __restrict__ o1, const float* __restrict__ wgt,
                     const float* __restrict__ bias, float* __restrict__ o2) {
  __shared__ float p[4096];
  int bc = blockIdx.x, c = bc & 127, tid = threadIdx.x;
  const float* src = o1 + (long)bc * 4096;
#pragma unroll
  for (int s4 = 0; s4 < 4; ++s4) {
    int off = s4 * 1024 + tid * 4;
    *(float4*)&p[off] = *(const float4*)&src[off];
  }
  float wr[9];
#pragma unroll
  for (int j = 0; j < 9; ++j) wr[j] = wgt[c * 9 + j];
  float bv = bias[c];
  __syncthreads();
  int wg = tid & 15, hs = tid >> 4;
  int w0 = wg * 4, h0 = hs * 4;
  float in[6][6];
#pragma unroll
  for (int ri = 0; ri < 6; ++ri) {
    int h = h0 - 1 + ri;
    if (h < 0 || h > 63) {
#pragma unroll
      for (int ci = 0; ci < 6; ++ci) in[ri][ci] = 0.f;
    } else {
      float4 cc = *(float4*)&p[h * 64 + w0];
      in[ri][1] = cc.x; in[ri][2] = cc.y; in[ri][3] = cc.z; in[ri][4] = cc.w;
      in[ri][0] = (w0 > 0) ? p[h * 64 + w0 - 1] : 0.f;
      in[ri][5] = (w0 < 60) ? p[h * 64 + w0 + 4] : 0.f;
    }
  }
#pragma unroll
  for (int r = 0; r < 4; ++r) {
    float oc[4];
#pragma unroll
    for (int q = 0; q < 4; ++q) {
      float acc = bv;
#pragma unroll
      for (int dh = 0; dh < 3; ++dh)
#pragma unroll
        for (int dq = 0; dq < 3; ++dq)
          acc += in[r + dh][q + dq] * wr[dh * 3 + dq];
      oc[q] = siluf(acc);
    }
    *(float4*)&o2[(long)bc * 4096 + (h0 + r) * 64 + w0] =
        make_float4(oc[0], oc[1], oc[2], oc[3]);
  }
}

// K3: s[b,l,d] = sum_c o2[b,c,l]*w[c,d]  (d<32). 4x2 micro-tiles.
__global__ void k_fcin(const float* __restrict__ o2, const float* __restrict__ w,
                       float* __restrict__ s) {
  __shared__ float xt[128][64];
  __shared__ float wt[128][32];
  int b = blockIdx.y, l0 = blockIdx.x * 64;
  int tid = threadIdx.x;
  int f4 = (tid & 15) * 4, r0 = tid >> 4;
#pragma unroll
  for (int st = 0; st < 8; ++st) {
    int r = r0 + st * 16;
    *(float4*)&xt[r][f4] = *(const float4*)&o2[((long)b * 128 + r) * 4096 + l0 + f4];
  }
  int f4w = (tid & 7) * 4, rw = tid >> 3;
#pragma unroll
  for (int st = 0; st < 4; ++st) {
    int r = rw + st * 32;
    *(float4*)&wt[r][f4w] = *(const float4*)&w[r * 32 + f4w];
  }
  __syncthreads();
  int tx = tid & 15, ty = tid >> 4;
  int c0 = tx * 4, d0 = ty * 2;
  float acc[2][4] = {};
  for (int k = 0; k < 128; ++k) {
    float4 xv = *(float4*)&xt[k][c0];
    float2 wv = *(float2*)&wt[k][d0];
    float xa[4] = {xv.x, xv.y, xv.z, xv.w};
#pragma unroll
    for (int q = 0; q < 4; ++q) {
      acc[0][q] += wv.x * xa[q];
      acc[1][q] += wv.y * xa[q];
    }
  }
#pragma unroll
  for (int q = 0; q < 4; ++q) {
    long ob = ((long)b * 4096 + l0 + c0 + q) * 32 + d0;
    *(float2*)&s[ob] = make_float2(acc[0][q], acc[1][q]);
  }
}

// K4: in_proj (MFMA bf16, K=32) + causal conv1d + silu + dt softplus + cum.
// r9 post-mortem: the VALU version was LDS-b128-broadcast bound (536 b128/wave
// ~6.4K cyc). MFMA A/B frags come straight from GLOBAL (each s element read
// once; W gathers are L2-hot 64B segments). Only LDS: bf16 transpose buffer
// xbcL for the conv (26KB -> 6 blocks/CU). Wave mt owns col-tiles mt*4..mt*4+3;
// wave 0 also tile 16 (the dt column, cols>=257 predicated to 0). Phase 2:
// waves 0-2 = rolling-window conv from xbcL; wave 3 = dt softplus+prefix scan.
__global__ __launch_bounds__(256) void k_inprojconv(
    const float* __restrict__ s, const float* __restrict__ Win,
    const float* __restrict__ conv_w, const float* __restrict__ conv_b,
    const float* __restrict__ dt_bias, const float* __restrict__ A_log,
    float* __restrict__ z, float* __restrict__ xbca,
    float* __restrict__ dts, float* __restrict__ cum) {
  __shared__ unsigned short xbcL[67][194];   // pre-conv xbc, bf16
  __shared__ float dtL[64];
  int dir = blockIdx.z, b = blockIdx.y, l0 = blockIdx.x * 64;
  int tid = threadIdx.x, lane = tid & 63, mt = tid >> 6;
  int q = lane >> 4, i = lane & 15;
  const float* W = Win + (long)dir * 32 * 257;
  long rowbase = (long)b * 4096 + l0;
  float* zp = z + (long)dir * ZSTRIDE;

  // A-frags: rows rr = 16rt + i (seq l = l0-3+rr, flip-resolved), k = q*8+j
  short8 afr[5];
#pragma unroll
  for (int rt = 0; rt < 5; ++rt) {
    int rr = 16 * rt + i;
    int l = l0 - 3 + rr;
    union { unsigned short us[8]; short8 s8; } cv;
    if (l >= 0 && l < 4096) {
      int lsrc = dir ? (4095 - l) : l;
      const float* sp = &s[((long)b * 4096 + lsrc) * 32 + q * 8];
      float4 v0 = *(const float4*)sp;
      float4 v1 = *(const float4*)(sp + 4);
      cv.us[0] = tobf(v0.x); cv.us[1] = tobf(v0.y);
      cv.us[2] = tobf(v0.z); cv.us[3] = tobf(v0.w);
      cv.us[4] = tobf(v1.x); cv.us[5] = tobf(v1.y);
      cv.us[6] = tobf(v1.z); cv.us[7] = tobf(v1.w);
    } else {
#pragma unroll
      for (int j2 = 0; j2 < 8; ++j2) cv.us[j2] = 0;
    }
    afr[rt] = cv.s8;
  }

  int nct = (mt == 0) ? 5 : 4;
  for (int cti = 0; cti < nct; ++cti) {
    int ct = (cti < 4) ? (mt * 4 + cti) : 16;
    int n = 16 * ct + i;                      // output column (B row)
    union { unsigned short us[8]; short8 s8; } bv;
#pragma unroll
    for (int j2 = 0; j2 < 8; ++j2)
      bv.us[j2] = (n < 257) ? tobf(W[(q * 8 + j2) * 257 + n]) : (unsigned short)0;
#pragma unroll
    for (int rt = 0; rt < 5; ++rt) {
      f32x4 d = {0.f, 0.f, 0.f, 0.f};
      d = __builtin_amdgcn_mfma_f32_16x16x32_bf16(afr[rt], bv.s8, d, 0, 0, 0);
#pragma unroll
      for (int r2 = 0; r2 < 4; ++r2) {
        int rr = 16 * rt + q * 4 + r2;
        if (ct < 4) {                         // z columns 0..63
          if (rr >= 3 && rr <= 66)
            zp[(rowbase + rr - 3) * 64 + n] = d[r2];
        } else if (ct < 16) {                 // xbc columns 0..191 (pre-conv)
          if (rr <= 66)
            xbcL[rr][n - 64] = tobf(d[r2]);
        } else {                              // dt column (n==256 only)
          if (i == 0 && rr >= 3 && rr <= 66)
            dtL[rr - 3] = d[r2];
        }
      }
    }
  }
  __syncthreads();

  if (tid < 192) {
    // rolling-window causal conv-4 + bias + silu, one channel per thread
    int c = tid;
    float cw0 = conv_w[dir * 768 + c * 4 + 0];
    float cw1 = conv_w[dir * 768 + c * 4 + 1];
    float cw2 = conv_w[dir * 768 + c * 4 + 2];
    float cw3 = conv_w[dir * 768 + c * 4 + 3];
    float cb2 = conv_b[dir * 192 + c];
    float* xp = xbca + (long)dir * XSTRIDE;
    float win0 = 0.f, win1 = 0.f, win2 = 0.f, win3 = 0.f;
    for (int rr = 0; rr < 67; ++rr) {
      float a = frombf(xbcL[rr][c]);
      win0 = win1; win1 = win2; win2 = win3; win3 = a;
      if (rr >= 3) {
        float acc = cb2 + win0 * cw0 + win1 * cw1 + win2 * cw2 + win3 * cw3;
        xp[(rowbase + rr - 3) * 192 + c] = siluf(acc);
      }
    }
  } else {
    // dt: softplus + wave prefix scan of log-decay (wave 3, lanes 0..63)
    int ln = tid - 192;
    float v = dtL[ln] + dt_bias[dir];
    float sp = (v > 20.f) ? v : log1pf(expf(v));
    dts[dir * 32768 + rowbase + ln] = sp;
    float cd = -expf(A_log[dir]) * sp;
#pragma unroll
    for (int off = 1; off < 64; off <<= 1) {
      float u = __shfl_up(cd, off);
      if (ln >= off) cd += u;
    }
    cum[dir * 32768 + rowbase + ln] = cd;
  }
}

// K6: chunk summary T[p][n] = sum_s f_s*X_s[p]*B_s[n].
__global__ void k_chunkT(const float* __restrict__ xbca, const float* __restrict__ dts,
                         const float* __restrict__ cum, float* __restrict__ T) {
  __shared__ float Xs[64][68], Bs[64][68];
  int dir = blockIdx.y;
  int bk = blockIdx.x, b = bk >> 6, k = bk & 63;
  int tid = threadIdx.x, lane = tid & 63, grp = tid >> 6;
  const float* xp = xbca + (long)dir * XSTRIDE;
  const float* dtp = dts + dir * 32768;
  const float* cp = cum + dir * 32768;
  long base = (long)b * 4096 + (long)k * 64;
  float clend = cp[base + 63];
  for (int r = grp; r < 64; r += 4) {
    float f = expf(clend - cp[base + r]) * dtp[base + r];
    Xs[r][lane] = xp[(base + r) * 192 + lane] * f;
    Bs[r][lane] = xp[(base + r) * 192 + 64 + lane];
  }
  __syncthreads();
  int tx = tid & 15, ty = tid >> 4;
  int p0 = ty * 4, n0 = tx * 4;
  float acc[4][4] = {};
  for (int s = 0; s < 64; ++s) {
    float4 xv = *(float4*)&Xs[s][p0];
    float4 bv = *(float4*)&Bs[s][n0];
    float xa[4] = {xv.x, xv.y, xv.z, xv.w};
    float ba[4] = {bv.x, bv.y, bv.z, bv.w};
#pragma unroll
    for (int a = 0; a < 4; ++a)
#pragma unroll
      for (int q = 0; q < 4; ++q) acc[a][q] += xa[a] * ba[q];
  }
#pragma unroll
  for (int a = 0; a < 4; ++a)
    *(float4*)&T[(long)dir * TSTRIDE + (long)bk * 4096 + (p0 + a) * 64 + n0] =
        make_float4(acc[a][0], acc[a][1], acc[a][2], acc[a][3]);
}

// K7: inter-chunk state scan (both dirs)
__global__ void k_scan(const float* __restrict__ T, const float* __restrict__ cum,
                       float* __restrict__ Sprev) {
  int idx = blockIdx.x * 256 + threadIdx.x;   // 65536
  int dir = idx >> 15, rem = idx & 32767;
  int b = rem >> 12, pn = rem & 4095;
  const float* Tp = T + (long)dir * TSTRIDE;
  float* Sp = Sprev + (long)dir * TSTRIDE;
  const float* cp = cum + dir * 32768 + b * 4096;
  float sacc = 0.f;
  for (int k = 0; k < 64; ++k) {
    long o = ((long)(b * 64 + k)) * 4096 + pn;
    Sp[o] = sacc;
    sacc = expf(cp[k * 64 + 63]) * sacc + Tp[o];
  }
}

// K8: per-chunk Y + gate + RMSNorm + out-proj — MFMA bf16 version.
__global__ __launch_bounds__(256) void k_chunkYout(
    const float* __restrict__ xbca, const float* __restrict__ dts,
    const float* __restrict__ cum, const float* __restrict__ Sprev,
    const float* __restrict__ Dp, const float* __restrict__ z,
    const float* __restrict__ normw, const float* __restrict__ Wout,
    float* __restrict__ s2a, float* __restrict__ s2b) {
  __shared__ unsigned short Cb[64][72];    // C[t][n]   (b128 frags)
  __shared__ unsigned short Bop[64][66];   // Bdt -> Sprev -> X^T (b32 frags)
  __shared__ unsigned short Gb[64][72];    // G[t][s] -> Yn[t][p] (b128 frags)
  __shared__ unsigned short WnT[32][66];   // Wn^T[d][p]
  __shared__ float cumS[64];
  int dir = blockIdx.y;
  int bk = blockIdx.x, b = bk >> 6, k = bk & 63;
  int tid = threadIdx.x, lane = tid & 63, mt = tid >> 6;
  int q = lane >> 4, i = lane & 15;
  const float* xp = xbca + (long)dir * XSTRIDE;
  const float* dtp = dts + dir * 32768;
  const float* cp = cum + dir * 32768;
  const float* Sp = Sprev + (long)dir * TSTRIDE;
  const float* zp = z + (long)dir * ZSTRIDE;
  long base = (long)b * 4096 + (long)k * 64;

  for (int r = mt; r < 64; r += 4) {
    float dtv = dtp[base + r];
    Cb[r][lane]  = tobf(xp[(base + r) * 192 + 128 + lane]);
    Bop[r][lane] = tobf(xp[(base + r) * 192 + 64 + lane] * dtv);
  }
  for (int idx = tid; idx < 2048; idx += 256) {
    int p = idx >> 5, d = idx & 31;
    WnT[d][p] = tobf(normw[dir * 64 + p] * Wout[(long)dir * 2048 + p * 32 + d]);
  }
  if (tid < 64) cumS[tid] = cp[base + tid];
  __syncthreads();

  short8 a0 = *(const short8*)&Cb[mt * 16 + i][q * 8];
  short8 a1 = *(const short8*)&Cb[mt * 16 + i][q * 8 + 32];

#pragma unroll
  for (int lt = 0; lt < 4; ++lt) {
    short8 b0 = ldfrag66(&Bop[lt * 16 + i][0], q * 8);
    short8 b1 = ldfrag66(&Bop[lt * 16 + i][0], q * 8 + 32);
    f32x4 d = {0.f, 0.f, 0.f, 0.f};
    d = __builtin_amdgcn_mfma_f32_16x16x32_bf16(a0, b0, d, 0, 0, 0);
    d = __builtin_amdgcn_mfma_f32_16x16x32_bf16(a1, b1, d, 0, 0, 0);
#pragma unroll
    for (int r2 = 0; r2 < 4; ++r2) {
      int t = mt * 16 + q * 4 + r2;
      int l = lt * 16 + i;
      float g = (l <= t) ? d[r2] * expf(cumS[t] - cumS[l]) : 0.f;
      Gb[t][l] = tobf(g);
    }
  }
  __syncthreads();

  for (int r = mt; r < 64; r += 4)
    Bop[r][lane] = tobf(Sp[(long)bk * 4096 + r * 64 + lane]);
  __syncthreads();

  f32x4 dint[4];
#pragma unroll
  for (int lt = 0; lt < 4; ++lt) {
    short8 b0 = ldfrag66(&Bop[lt * 16 + i][0], q * 8);
    short8 b1 = ldfrag66(&Bop[lt * 16 + i][0], q * 8 + 32);
    f32x4 d = {0.f, 0.f, 0.f, 0.f};
    d = __builtin_amdgcn_mfma_f32_16x16x32_bf16(a0, b0, d, 0, 0, 0);
    d = __builtin_amdgcn_mfma_f32_16x16x32_bf16(a1, b1, d, 0, 0, 0);
    dint[lt] = d;
  }
  __syncthreads();

#pragma unroll
  for (int j = 0; j < 8; ++j) {
    int s = mt * 16 + 2 * j;
    float x0 = xp[(base + s) * 192 + lane];
    float x1 = xp[(base + s + 1) * 192 + lane];
    unsigned int pk = (unsigned int)tobf(x0) | ((unsigned int)tobf(x1) << 16);
    *(unsigned int*)&Bop[lane][s] = pk;
  }
  __syncthreads();

  short8 g0 = *(const short8*)&Gb[mt * 16 + i][q * 8];
  short8 g1 = *(const short8*)&Gb[mt * 16 + i][q * 8 + 32];
  float Dv = Dp[dir];
  float yv[4][4];
  float rowss[4] = {0.f, 0.f, 0.f, 0.f};
#pragma unroll
  for (int lt = 0; lt < 4; ++lt) {
    short8 b0 = ldfrag66(&Bop[lt * 16 + i][0], q * 8);
    short8 b1 = ldfrag66(&Bop[lt * 16 + i][0], q * 8 + 32);
    f32x4 d = {0.f, 0.f, 0.f, 0.f};
    d = __builtin_amdgcn_mfma_f32_16x16x32_bf16(g0, b0, d, 0, 0, 0);
    d = __builtin_amdgcn_mfma_f32_16x16x32_bf16(g1, b1, d, 0, 0, 0);
#pragma unroll
    for (int r2 = 0; r2 < 4; ++r2) {
      int t = mt * 16 + q * 4 + r2;
      int p = lt * 16 + i;
      float et = expf(cumS[t]);
      float xv = xp[(base + t) * 192 + p];
      float y = d[r2] + et * dint[lt][r2] + Dv * xv;
      float zv = zp[(base + t) * 64 + p];
      float v = y * siluf(zv);
      yv[lt][r2] = v;
      rowss[r2] += v * v;
    }
  }
#pragma unroll
  for (int m = 1; m < 16; m <<= 1) {
#pragma unroll
    for (int r2 = 0; r2 < 4; ++r2) rowss[r2] += __shfl_xor(rowss[r2], m);
  }
  float rscv[4];
#pragma unroll
  for (int r2 = 0; r2 < 4; ++r2)
    rscv[r2] = rsqrtf(rowss[r2] * (1.0f / 64.0f) + 1e-5f);
#pragma unroll
  for (int lt = 0; lt < 4; ++lt)
#pragma unroll
    for (int r2 = 0; r2 < 4; ++r2) {
      int t = mt * 16 + q * 4 + r2;
      int p = lt * 16 + i;
      Gb[t][p] = tobf(yv[lt][r2] * rscv[r2]);
    }
  __syncthreads();

  short8 y0 = *(const short8*)&Gb[mt * 16 + i][q * 8];
  short8 y1 = *(const short8*)&Gb[mt * 16 + i][q * 8 + 32];
  float* s2x = dir ? s2b : s2a;
#pragma unroll
  for (int dt = 0; dt < 2; ++dt) {
    short8 b0 = ldfrag66(&WnT[dt * 16 + i][0], q * 8);
    short8 b1 = ldfrag66(&WnT[dt * 16 + i][0], q * 8 + 32);
    f32x4 d = {0.f, 0.f, 0.f, 0.f};
    d = __builtin_amdgcn_mfma_f32_16x16x32_bf16(y0, b0, d, 0, 0, 0);
    d = __builtin_amdgcn_mfma_f32_16x16x32_bf16(y1, b1, d, 0, 0, 0);
#pragma unroll
    for (int r2 = 0; r2 < 4; ++r2) {
      int tl = mt * 16 + q * 4 + r2;
      int l = k * 64 + tl;
      int lout = dir ? (4095 - l) : l;
      int dd = dt * 16 + i;
      s2x[((long)b * 4096 + lout) * 32 + dd] = d[r2];
    }
  }
}

// K10: o3 = (s2a+s2b)@W — pure GEMM.
__global__ void k_fcout(const float* __restrict__ s2a, const float* __restrict__ s2b,
                        const float* __restrict__ w, float* __restrict__ o3) {
  __shared__ float st[32][68];
  __shared__ float wt[32][64];
  int b = blockIdx.y, l0 = blockIdx.x * 64, cb = blockIdx.z * 64;
  int tid = threadIdx.x;
  {
    int d = tid & 31, l = tid >> 5;
    for (int si = 0; si < 8; ++si) {
      int ll = l + si * 8;
      long o = ((long)b * 4096 + l0 + ll) * 32 + d;
      st[d][ll] = s2a[o] + s2b[o];
    }
    int f4 = (tid & 15) * 4, r = tid >> 4;
    for (int si = 0; si < 2; ++si) {
      int rr = r + si * 16;
      *(float4*)&wt[rr][f4] = *(const float4*)&w[rr * 128 + cb + f4];
    }
  }
  __syncthreads();
  int tx = tid & 15, ty = tid >> 4;
  int c0 = tx * 4, t0 = ty * 4;
  float acc[4][4] = {};
  for (int k = 0; k < 32; ++k) {
    float4 xv = *(float4*)&st[k][c0];
    float4 wv = *(float4*)&wt[k][t0];
    float xa[4] = {xv.x, xv.y, xv.z, xv.w};
    float wa[4] = {wv.x, wv.y, wv.z, wv.w};
#pragma unroll
    for (int a = 0; a < 4; ++a)
#pragma unroll
      for (int q = 0; q < 4; ++q) acc[a][q] += wa[a] * xa[q];
  }
#pragma unroll
  for (int a = 0; a < 4; ++a)
    *(float4*)&o3[((long)b * 128 + cb + t0 + a) * 4096 + l0 + c0] =
        make_float4(acc[a][0], acc[a][1], acc[a][2], acc[a][3]);
}

// K10b: per-channel sums for BatchNorm (2 atomics per block)
__global__ void k_bnstat(const float* __restrict__ o3, float* __restrict__ stats) {
  int bc = blockIdx.x;  // 1024 = (b,c)
  int tid = threadIdx.x;
  const float* p = o3 + (long)bc * 4096;
  float s = 0.f, q = 0.f;
  for (int i = tid * 4; i < 4096; i += 1024) {
    float4 v = *(const float4*)&p[i];
    s += v.x + v.y + v.z + v.w;
    q += v.x * v.x + v.y * v.y + v.z * v.z + v.w * v.w;
  }
  __shared__ float rs[4], rq[4];
  for (int off = 32; off; off >>= 1) { s += __shfl_down(s, off); q += __shfl_down(q, off); }
  if ((tid & 63) == 0) { rs[tid >> 6] = s; rq[tid >> 6] = q; }
  __syncthreads();
  if (tid == 0) {
    float a = rs[0] + rs[1] + rs[2] + rs[3];
    float b2 = rq[0] + rq[1] + rq[2] + rq[3];
    int c = bc & 127;
    atomicAdd(&stats[c], a);
    atomicAdd(&stats[128 + c], b2);
  }
}

// K12: BN + conv4 (128->128) + sigmoid + gated residual. 4x4 micro-tiles.
__global__ void k_final(const float* __restrict__ o3, const float* __restrict__ stats,
                        const float* __restrict__ bng, const float* __restrict__ bnb,
                        const float* __restrict__ w, const float* __restrict__ bias,
                        const float* __restrict__ x, float* __restrict__ out) {
  __shared__ float xt[128][64];
  __shared__ float wt[128][64];
  __shared__ float sc[128], sh[128];
  int b = blockIdx.y, l0 = blockIdx.x * 64, cb = blockIdx.z * 64;
  int tid = threadIdx.x;
  if (tid < 128) {
    float mu = stats[tid] * (1.0f / 32768.0f);
    float var = stats[128 + tid] * (1.0f / 32768.0f) - mu * mu;
    float r = rsqrtf(var + 1e-5f);
    sc[tid] = r * bng[tid];
    sh[tid] = bnb[tid] - mu * r * bng[tid];
  }
  __syncthreads();
  int f4 = (tid & 15) * 4, r0 = tid >> 4;
#pragma unroll
  for (int s = 0; s < 8; ++s) {
    int r = r0 + s * 16;
    float4 v = *(const float4*)&o3[((long)b * 128 + r) * 4096 + l0 + f4];
    float scr = sc[r], shr = sh[r];
    *(float4*)&xt[r][f4] = make_float4(fmaf(v.x, scr, shr), fmaf(v.y, scr, shr),
                                       fmaf(v.z, scr, shr), fmaf(v.w, scr, shr));
    *(float4*)&wt[r][f4] = *(const float4*)&w[r * 128 + cb + f4];
  }
  __syncthreads();
  int tx = tid & 15, ty = tid >> 4;
  int c0 = tx * 4, t0 = ty * 4;
  float acc[4][4];
#pragma unroll
  for (int a = 0; a < 4; ++a) {
    float bv = bias[cb + t0 + a];
#pragma unroll
    for (int q = 0; q < 4; ++q) acc[a][q] = bv;
  }
  for (int k = 0; k < 128; ++k) {
    float4 xv = *(float4*)&xt[k][c0];
    float4 wv = *(float4*)&wt[k][t0];
    float xa[4] = {xv.x, xv.y, xv.z, xv.w};
    float wa[4] = {wv.x, wv.y, wv.z, wv.w};
#pragma unroll
    for (int a = 0; a < 4; ++a)
#pragma unroll
      for (int q = 0; q < 4; ++q) acc[a][q] += wa[a] * xa[q];
  }
#pragma unroll
  for (int a = 0; a < 4; ++a) {
    long xi = ((long)b * 128 + cb + t0 + a) * 4096 + l0 + c0;
    float4 xv = *(const float4*)&x[xi];
    float4 o4;
    o4.x = xv.x * (1.0f + 1.0f / (1.0f + expf(-acc[a][0])));
    o4.y = xv.y * (1.0f + 1.0f / (1.0f + expf(-acc[a][1])));
    o4.z = xv.z * (1.0f + 1.0f / (1.0f + expf(-acc[a][2])));
    o4.w = xv.w * (1.0f + 1.0f / (1.0f + expf(-acc[a][3])));
    *(float4*)&out[xi] = o4;
  }
}

extern "C" void kernel_launch(void* const* d_in, const int* in_sizes, int n_in,
                              void* d_out, int out_size, void* d_ws, size_t ws_size,
                              hipStream_t stream) {
  const float* x          = (const float*)d_in[0];
  const float* lin1_w     = (const float*)d_in[1];
  const float* lin1_b     = (const float*)d_in[2];
  const float* dw_w       = (const float*)d_in[3];
  const float* dw_b       = (const float*)d_in[4];
  const float* fc_in_w    = (const float*)d_in[5];
  const float* mam_in_w   = (const float*)d_in[6];
  const float* mam_conv_w = (const float*)d_in[7];
  const float* mam_conv_b = (const float*)d_in[8];
  const float* mam_dt_bias= (const float*)d_in[9];
  const float* mam_A_log  = (const float*)d_in[10];
  const float* mam_D      = (const float*)d_in[11];
  const float* mam_norm_w = (const float*)d_in[12];
  const float* mam_out_w  = (const float*)d_in[13];
  const float* fc_out_w   = (const float*)d_in[14];
  const float* bn_g       = (const float*)d_in[15];
  const float* bn_b       = (const float*)d_in[16];
  const float* conv4_w    = (const float*)d_in[17];
  const float* conv4_b    = (const float*)d_in[18];
  float* out = (float*)d_out;
  float* ws  = (float*)d_ws;

  float* o1   = ws + OFF_O1;
  float* o2   = ws + OFF_O2;
  float* sbuf = ws + OFF_S;
  float* zbuf = ws + OFF_Z;
  float* xbca = ws + OFF_XBCA;
  float* dts  = ws + OFF_DTS;
  float* cum  = ws + OFF_CUM;
  float* Tbuf = ws + OFF_T;
  float* Sprev= ws + OFF_SPREV;
  float* s2a  = ws + OFF_S2A;
  float* s2b  = ws + OFF_S2B;
  float* bnst = ws + OFF_BN;
  float* o3   = ws + OFF_O3;

  hipMemsetAsync(bnst, 0, 256 * sizeof(float), stream);

  k_lin1<<<dim3(64, 8, 2), 256, 0, stream>>>(x, lin1_w, lin1_b, o1);
  k_dw<<<1024, 256, 0, stream>>>(o1, dw_w, dw_b, o2);
  k_fcin<<<dim3(64, 8), 256, 0, stream>>>(o2, fc_in_w, sbuf);
  k_inprojconv<<<dim3(64, 8, 2), 256, 0, stream>>>(sbuf, mam_in_w, mam_conv_w, mam_conv_b,
                                                   mam_dt_bias, mam_A_log,
                                                   zbuf, xbca, dts, cum);
  k_chunkT<<<dim3(512, 2), 256, 0, stream>>>(xbca, dts, cum, Tbuf);
  k_scan<<<256, 256, 0, stream>>>(Tbuf, cum, Sprev);
  k_chunkYout<<<dim3(512, 2), 256, 0, stream>>>(xbca, dts, cum, Sprev, mam_D, zbuf,
                                                mam_norm_w, mam_out_w, s2a, s2b);
  k_fcout<<<dim3(64, 8, 2), 256, 0, stream>>>(s2a, s2b, fc_out_w, o3);
  k_bnstat<<<1024, 256, 0, stream>>>(o3, bnst);
  k_final<<<dim3(64, 8, 2), 256, 0, stream>>>(o3, bnst, bn_g, bn_b, conv4_w, conv4_b, x, out);
}

// Round 11
// 248.459 us; speedup vs baseline: 1.2705x; 1.1099x over previous
//
#include <hip/hip_runtime.h>
#include <math.h>

// Problem constants
constexpr int Bn = 8, Cn = 128, Ln = 4096;

// Workspace layout (float offsets). z and xbca are stored as bf16 (ushort)
// inside their (over-sized) regions.
constexpr size_t OFF_O1   = 0;          // o1; later o3 (aliased)
constexpr size_t OFF_O2   = 4194304;
constexpr size_t OFF_S    = 8388608;
constexpr size_t OFF_Z    = 9437184;    // bf16: 2 dirs x 2,097,152 ushort
constexpr size_t OFF_XBCA = 13631488;   // bf16: 2 dirs x 6,291,456 ushort
constexpr size_t OFF_DTS  = 26214400;
constexpr size_t OFF_CUM  = 26279936;
constexpr size_t OFF_T    = 26345472;   // 2 dirs x 2,097,152
constexpr size_t OFF_SPREV= 30539776;   // 2 dirs x 2,097,152
constexpr size_t OFF_S2A  = 34734080;
constexpr size_t OFF_S2B  = 35782656;
constexpr size_t OFF_BN   = 36831232;
constexpr size_t OFF_O3   = 0;

constexpr long ZSTRIDE_H = 2097152;   // ushort elements per dir
constexpr long XSTRIDE_H = 6291456;   // ushort elements per dir
constexpr long TSTRIDE = 2097152;

typedef __attribute__((ext_vector_type(8))) short short8;
typedef __attribute__((ext_vector_type(4))) float f32x4;

__device__ __forceinline__ float siluf(float v) { return v / (1.0f + expf(-v)); }

__device__ __forceinline__ unsigned short tobf(float f) {
  unsigned int u = __float_as_uint(f);
  u += 0x7FFFu + ((u >> 16) & 1u);     // RNE
  return (unsigned short)(u >> 16);
}

__device__ __forceinline__ float frombf(unsigned short u) {
  return __uint_as_float(((unsigned int)u) << 16);
}

// 8 consecutive bf16 from LDS via 4 dword reads (>=4B-aligned offsets)
__device__ __forceinline__ short8 ldfrag(const unsigned short* p) {
  union { unsigned int u[4]; short8 s; } cv;
  cv.u[0] = *(const unsigned int*)(p);
  cv.u[1] = *(const unsigned int*)(p + 2);
  cv.u[2] = *(const unsigned int*)(p + 4);
  cv.u[3] = *(const unsigned int*)(p + 6);
  return cv.s;
}

// K1: o1[b,c,l] = sum_k x[b,k,l]*w[k,c] + bias[c] — MFMA bf16, K=128.
// A[c][k]=w^T, B[l][k]=x^T staged bf16 at pitch 140 (8B-aligned frags, <=2-way banks).
__global__ __launch_bounds__(256) void k_lin1(const float* __restrict__ x,
                                              const float* __restrict__ w,
                                              const float* __restrict__ bias,
                                              float* __restrict__ o1) {
  __shared__ unsigned short wT[64][140];
  __shared__ unsigned short xT[64][140];
  int b = blockIdx.y, l0 = blockIdx.x * 64, cb = blockIdx.z * 64;
  int tid = threadIdx.x, lane = tid & 63, mt = tid >> 6;
  int q = lane >> 4, i = lane & 15;
  int c4 = (tid & 15) * 4, k0 = tid >> 4;
#pragma unroll
  for (int s = 0; s < 8; ++s) {
    int k = k0 + s * 16;
    float4 wv = *(const float4*)&w[k * 128 + cb + c4];
    wT[c4 + 0][k] = tobf(wv.x); wT[c4 + 1][k] = tobf(wv.y);
    wT[c4 + 2][k] = tobf(wv.z); wT[c4 + 3][k] = tobf(wv.w);
    float4 xv = *(const float4*)&x[((long)b * 128 + k) * 4096 + l0 + c4];
    xT[c4 + 0][k] = tobf(xv.x); xT[c4 + 1][k] = tobf(xv.y);
    xT[c4 + 2][k] = tobf(xv.z); xT[c4 + 3][k] = tobf(xv.w);
  }
  __syncthreads();
  short8 af[4];
#pragma unroll
  for (int kk = 0; kk < 4; ++kk)
    af[kk] = ldfrag(&wT[mt * 16 + i][q * 8 + 32 * kk]);
  float bv[4];
#pragma unroll
  for (int r2 = 0; r2 < 4; ++r2) bv[r2] = bias[cb + 16 * mt + q * 4 + r2];
#pragma unroll
  for (int nt = 0; nt < 4; ++nt) {
    f32x4 d = {0.f, 0.f, 0.f, 0.f};
#pragma unroll
    for (int kk = 0; kk < 4; ++kk) {
      short8 bfr = ldfrag(&xT[nt * 16 + i][q * 8 + 32 * kk]);
      d = __builtin_amdgcn_mfma_f32_16x16x32_bf16(af[kk], bfr, d, 0, 0, 0);
    }
#pragma unroll
    for (int r2 = 0; r2 < 4; ++r2) {
      int c = 16 * mt + q * 4 + r2;
      o1[((long)b * 128 + cb + c) * 4096 + l0 + nt * 16 + i] = d[r2] + bv[r2];
    }
  }
}

// K2: depthwise 3x3 SAME + bias + silu. 4x4 patch per thread from LDS plane.
__global__ void k_dw(const float* __restrict__ o1, const float* __restrict__ wgt,
                     const float* __restrict__ bias, float* __restrict__ o2) {
  __shared__ float p[4096];
  int bc = blockIdx.x, c = bc & 127, tid = threadIdx.x;
  const float* src = o1 + (long)bc * 4096;
#pragma unroll
  for (int s4 = 0; s4 < 4; ++s4) {
    int off = s4 * 1024 + tid * 4;
    *(float4*)&p[off] = *(const float4*)&src[off];
  }
  float wr[9];
#pragma unroll
  for (int j = 0; j < 9; ++j) wr[j] = wgt[c * 9 + j];
  float bv = bias[c];
  __syncthreads();
  int wg = tid & 15, hs = tid >> 4;
  int w0 = wg * 4, h0 = hs * 4;
  float in[6][6];
#pragma unroll
  for (int ri = 0; ri < 6; ++ri) {
    int h = h0 - 1 + ri;
    if (h < 0 || h > 63) {
#pragma unroll
      for (int ci = 0; ci < 6; ++ci) in[ri][ci] = 0.f;
    } else {
      float4 cc = *(float4*)&p[h * 64 + w0];
      in[ri][1] = cc.x; in[ri][2] = cc.y; in[ri][3] = cc.z; in[ri][4] = cc.w;
      in[ri][0] = (w0 > 0) ? p[h * 64 + w0 - 1] : 0.f;
      in[ri][5] = (w0 < 60) ? p[h * 64 + w0 + 4] : 0.f;
    }
  }
#pragma unroll
  for (int r = 0; r < 4; ++r) {
    float oc[4];
#pragma unroll
    for (int q = 0; q < 4; ++q) {
      float acc = bv;
#pragma unroll
      for (int dh = 0; dh < 3; ++dh)
#pragma unroll
        for (int dq = 0; dq < 3; ++dq)
          acc += in[r + dh][q + dq] * wr[dh * 3 + dq];
      oc[q] = siluf(acc);
    }
    *(float4*)&o2[(long)bc * 4096 + (h0 + r) * 64 + w0] =
        make_float4(oc[0], oc[1], oc[2], oc[3]);
  }
}

// K3: s[b,l,d] = sum_c o2[b,c,l]*w[c,d]  (d<32). 4x2 micro-tiles.
__global__ void k_fcin(const float* __restrict__ o2, const float* __restrict__ w,
                       float* __restrict__ s) {
  __shared__ float xt[128][64];
  __shared__ float wt[128][32];
  int b = blockIdx.y, l0 = blockIdx.x * 64;
  int tid = threadIdx.x;
  int f4 = (tid & 15) * 4, r0 = tid >> 4;
#pragma unroll
  for (int st = 0; st < 8; ++st) {
    int r = r0 + st * 16;
    *(float4*)&xt[r][f4] = *(const float4*)&o2[((long)b * 128 + r) * 4096 + l0 + f4];
  }
  int f4w = (tid & 7) * 4, rw = tid >> 3;
#pragma unroll
  for (int st = 0; st < 4; ++st) {
    int r = rw + st * 32;
    *(float4*)&wt[r][f4w] = *(const float4*)&w[r * 32 + f4w];
  }
  __syncthreads();
  int tx = tid & 15, ty = tid >> 4;
  int c0 = tx * 4, d0 = ty * 2;
  float acc[2][4] = {};
  for (int k = 0; k < 128; ++k) {
    float4 xv = *(float4*)&xt[k][c0];
    float2 wv = *(float2*)&wt[k][d0];
    float xa[4] = {xv.x, xv.y, xv.z, xv.w};
#pragma unroll
    for (int q = 0; q < 4; ++q) {
      acc[0][q] += wv.x * xa[q];
      acc[1][q] += wv.y * xa[q];
    }
  }
#pragma unroll
  for (int q = 0; q < 4; ++q) {
    long ob = ((long)b * 4096 + l0 + c0 + q) * 32 + d0;
    *(float2*)&s[ob] = make_float2(acc[0][q], acc[1][q]);
  }
}

// K4: in_proj (MFMA bf16, K=32) + causal conv1d + silu + dt softplus + cum.
// z and xbca now written as bf16 (halves the 66MB write traffic).
__global__ __launch_bounds__(256) void k_inprojconv(
    const float* __restrict__ s, const float* __restrict__ Win,
    const float* __restrict__ conv_w, const float* __restrict__ conv_b,
    const float* __restrict__ dt_bias, const float* __restrict__ A_log,
    unsigned short* __restrict__ z, unsigned short* __restrict__ xbca,
    float* __restrict__ dts, float* __restrict__ cum) {
  __shared__ unsigned short xbcL[67][194];   // pre-conv xbc, bf16
  __shared__ float dtL[64];
  int dir = blockIdx.z, b = blockIdx.y, l0 = blockIdx.x * 64;
  int tid = threadIdx.x, lane = tid & 63, mt = tid >> 6;
  int q = lane >> 4, i = lane & 15;
  const float* W = Win + (long)dir * 32 * 257;
  long rowbase = (long)b * 4096 + l0;
  unsigned short* zp = z + (long)dir * ZSTRIDE_H;

  short8 afr[5];
#pragma unroll
  for (int rt = 0; rt < 5; ++rt) {
    int rr = 16 * rt + i;
    int l = l0 - 3 + rr;
    union { unsigned short us[8]; short8 s8; } cv;
    if (l >= 0 && l < 4096) {
      int lsrc = dir ? (4095 - l) : l;
      const float* sp = &s[((long)b * 4096 + lsrc) * 32 + q * 8];
      float4 v0 = *(const float4*)sp;
      float4 v1 = *(const float4*)(sp + 4);
      cv.us[0] = tobf(v0.x); cv.us[1] = tobf(v0.y);
      cv.us[2] = tobf(v0.z); cv.us[3] = tobf(v0.w);
      cv.us[4] = tobf(v1.x); cv.us[5] = tobf(v1.y);
      cv.us[6] = tobf(v1.z); cv.us[7] = tobf(v1.w);
    } else {
#pragma unroll
      for (int j2 = 0; j2 < 8; ++j2) cv.us[j2] = 0;
    }
    afr[rt] = cv.s8;
  }

  int nct = (mt == 0) ? 5 : 4;
  for (int cti = 0; cti < nct; ++cti) {
    int ct = (cti < 4) ? (mt * 4 + cti) : 16;
    int n = 16 * ct + i;
    union { unsigned short us[8]; short8 s8; } bv;
#pragma unroll
    for (int j2 = 0; j2 < 8; ++j2)
      bv.us[j2] = (n < 257) ? tobf(W[(q * 8 + j2) * 257 + n]) : (unsigned short)0;
#pragma unroll
    for (int rt = 0; rt < 5; ++rt) {
      f32x4 d = {0.f, 0.f, 0.f, 0.f};
      d = __builtin_amdgcn_mfma_f32_16x16x32_bf16(afr[rt], bv.s8, d, 0, 0, 0);
#pragma unroll
      for (int r2 = 0; r2 < 4; ++r2) {
        int rr = 16 * rt + q * 4 + r2;
        if (ct < 4) {
          if (rr >= 3 && rr <= 66)
            zp[(rowbase + rr - 3) * 64 + n] = tobf(d[r2]);
        } else if (ct < 16) {
          if (rr <= 66)
            xbcL[rr][n - 64] = tobf(d[r2]);
        } else {
          if (i == 0 && rr >= 3 && rr <= 66)
            dtL[rr - 3] = d[r2];
        }
      }
    }
  }
  __syncthreads();

  if (tid < 192) {
    int c = tid;
    float cw0 = conv_w[dir * 768 + c * 4 + 0];
    float cw1 = conv_w[dir * 768 + c * 4 + 1];
    float cw2 = conv_w[dir * 768 + c * 4 + 2];
    float cw3 = conv_w[dir * 768 + c * 4 + 3];
    float cb2 = conv_b[dir * 192 + c];
    unsigned short* xp = xbca + (long)dir * XSTRIDE_H;
    float win0 = 0.f, win1 = 0.f, win2 = 0.f, win3 = 0.f;
    for (int rr = 0; rr < 67; ++rr) {
      float a = frombf(xbcL[rr][c]);
      win0 = win1; win1 = win2; win2 = win3; win3 = a;
      if (rr >= 3) {
        float acc = cb2 + win0 * cw0 + win1 * cw1 + win2 * cw2 + win3 * cw3;
        xp[(rowbase + rr - 3) * 192 + c] = tobf(siluf(acc));
      }
    }
  } else {
    int ln = tid - 192;
    float v = dtL[ln] + dt_bias[dir];
    float sp = (v > 20.f) ? v : log1pf(expf(v));
    dts[dir * 32768 + rowbase + ln] = sp;
    float cd = -expf(A_log[dir]) * sp;
#pragma unroll
    for (int off = 1; off < 64; off <<= 1) {
      float u = __shfl_up(cd, off);
      if (ln >= off) cd += u;
    }
    cum[dir * 32768 + rowbase + ln] = cd;
  }
}

// K6: chunk summary T[p][n] = sum_s f_s*X_s[p]*B_s[n]. xbca now bf16.
__global__ void k_chunkT(const unsigned short* __restrict__ xbca,
                         const float* __restrict__ dts,
                         const float* __restrict__ cum, float* __restrict__ T) {
  __shared__ float Xs[64][68], Bs[64][68];
  int dir = blockIdx.y;
  int bk = blockIdx.x, b = bk >> 6, k = bk & 63;
  int tid = threadIdx.x, lane = tid & 63, grp = tid >> 6;
  const unsigned short* xp = xbca + (long)dir * XSTRIDE_H;
  const float* dtp = dts + dir * 32768;
  const float* cp = cum + dir * 32768;
  long base = (long)b * 4096 + (long)k * 64;
  float clend = cp[base + 63];
  for (int r = grp; r < 64; r += 4) {
    float f = expf(clend - cp[base + r]) * dtp[base + r];
    Xs[r][lane] = frombf(xp[(base + r) * 192 + lane]) * f;
    Bs[r][lane] = frombf(xp[(base + r) * 192 + 64 + lane]);
  }
  __syncthreads();
  int tx = tid & 15, ty = tid >> 4;
  int p0 = ty * 4, n0 = tx * 4;
  float acc[4][4] = {};
  for (int s = 0; s < 64; ++s) {
    float4 xv = *(float4*)&Xs[s][p0];
    float4 bv = *(float4*)&Bs[s][n0];
    float xa[4] = {xv.x, xv.y, xv.z, xv.w};
    float ba[4] = {bv.x, bv.y, bv.z, bv.w};
#pragma unroll
    for (int a = 0; a < 4; ++a)
#pragma unroll
      for (int q = 0; q < 4; ++q) acc[a][q] += xa[a] * ba[q];
  }
#pragma unroll
  for (int a = 0; a < 4; ++a)
    *(float4*)&T[(long)dir * TSTRIDE + (long)bk * 4096 + (p0 + a) * 64 + n0] =
        make_float4(acc[a][0], acc[a][1], acc[a][2], acc[a][3]);
}

// K7: inter-chunk state scan (both dirs)
__global__ void k_scan(const float* __restrict__ T, const float* __restrict__ cum,
                       float* __restrict__ Sprev) {
  int idx = blockIdx.x * 256 + threadIdx.x;   // 65536
  int dir = idx >> 15, rem = idx & 32767;
  int b = rem >> 12, pn = rem & 4095;
  const float* Tp = T + (long)dir * TSTRIDE;
  float* Sp = Sprev + (long)dir * TSTRIDE;
  const float* cp = cum + dir * 32768 + b * 4096;
  float sacc = 0.f;
  for (int k = 0; k < 64; ++k) {
    long o = ((long)(b * 64 + k)) * 4096 + pn;
    Sp[o] = sacc;
    sacc = expf(cp[k * 64 + 63]) * sacc + Tp[o];
  }
}

// K8: per-chunk Y + gate + RMSNorm + out-proj — MFMA bf16. xbca/z read as bf16.
__global__ __launch_bounds__(256) void k_chunkYout(
    const unsigned short* __restrict__ xbca, const float* __restrict__ dts,
    const float* __restrict__ cum, const float* __restrict__ Sprev,
    const float* __restrict__ Dp, const unsigned short* __restrict__ z,
    const float* __restrict__ normw, const float* __restrict__ Wout,
    float* __restrict__ s2a, float* __restrict__ s2b) {
  __shared__ unsigned short Cb[64][72];
  __shared__ unsigned short Bop[64][66];
  __shared__ unsigned short Gb[64][72];
  __shared__ unsigned short WnT[32][66];
  __shared__ float cumS[64];
  int dir = blockIdx.y;
  int bk = blockIdx.x, b = bk >> 6, k = bk & 63;
  int tid = threadIdx.x, lane = tid & 63, mt = tid >> 6;
  int q = lane >> 4, i = lane & 15;
  const unsigned short* xp = xbca + (long)dir * XSTRIDE_H;
  const float* dtp = dts + dir * 32768;
  const float* cp = cum + dir * 32768;
  const float* Sp = Sprev + (long)dir * TSTRIDE;
  const unsigned short* zp = z + (long)dir * ZSTRIDE_H;
  long base = (long)b * 4096 + (long)k * 64;

  for (int r = mt; r < 64; r += 4) {
    float dtv = dtp[base + r];
    Cb[r][lane]  = xp[(base + r) * 192 + 128 + lane];
    Bop[r][lane] = tobf(frombf(xp[(base + r) * 192 + 64 + lane]) * dtv);
  }
  for (int idx = tid; idx < 2048; idx += 256) {
    int p = idx >> 5, d = idx & 31;
    WnT[d][p] = tobf(normw[dir * 64 + p] * Wout[(long)dir * 2048 + p * 32 + d]);
  }
  if (tid < 64) cumS[tid] = cp[base + tid];
  __syncthreads();

  short8 a0 = *(const short8*)&Cb[mt * 16 + i][q * 8];
  short8 a1 = *(const short8*)&Cb[mt * 16 + i][q * 8 + 32];

#pragma unroll
  for (int lt = 0; lt < 4; ++lt) {
    short8 b0 = ldfrag(&Bop[lt * 16 + i][q * 8]);
    short8 b1 = ldfrag(&Bop[lt * 16 + i][q * 8 + 32]);
    f32x4 d = {0.f, 0.f, 0.f, 0.f};
    d = __builtin_amdgcn_mfma_f32_16x16x32_bf16(a0, b0, d, 0, 0, 0);
    d = __builtin_amdgcn_mfma_f32_16x16x32_bf16(a1, b1, d, 0, 0, 0);
#pragma unroll
    for (int r2 = 0; r2 < 4; ++r2) {
      int t = mt * 16 + q * 4 + r2;
      int l = lt * 16 + i;
      float g = (l <= t) ? d[r2] * expf(cumS[t] - cumS[l]) : 0.f;
      Gb[t][l] = tobf(g);
    }
  }
  __syncthreads();

  for (int r = mt; r < 64; r += 4)
    Bop[r][lane] = tobf(Sp[(long)bk * 4096 + r * 64 + lane]);
  __syncthreads();

  f32x4 dint[4];
#pragma unroll
  for (int lt = 0; lt < 4; ++lt) {
    short8 b0 = ldfrag(&Bop[lt * 16 + i][q * 8]);
    short8 b1 = ldfrag(&Bop[lt * 16 + i][q * 8 + 32]);
    f32x4 d = {0.f, 0.f, 0.f, 0.f};
    d = __builtin_amdgcn_mfma_f32_16x16x32_bf16(a0, b0, d, 0, 0, 0);
    d = __builtin_amdgcn_mfma_f32_16x16x32_bf16(a1, b1, d, 0, 0, 0);
    dint[lt] = d;
  }
  __syncthreads();

#pragma unroll
  for (int j = 0; j < 8; ++j) {
    int s = mt * 16 + 2 * j;
    unsigned int pk = (unsigned int)xp[(base + s) * 192 + lane] |
                      ((unsigned int)xp[(base + s + 1) * 192 + lane] << 16);
    *(unsigned int*)&Bop[lane][s] = pk;
  }
  __syncthreads();

  short8 g0 = *(const short8*)&Gb[mt * 16 + i][q * 8];
  short8 g1 = *(const short8*)&Gb[mt * 16 + i][q * 8 + 32];
  float Dv = Dp[dir];
  float yv[4][4];
  float rowss[4] = {0.f, 0.f, 0.f, 0.f};
#pragma unroll
  for (int lt = 0; lt < 4; ++lt) {
    short8 b0 = ldfrag(&Bop[lt * 16 + i][q * 8]);
    short8 b1 = ldfrag(&Bop[lt * 16 + i][q * 8 + 32]);
    f32x4 d = {0.f, 0.f, 0.f, 0.f};
    d = __builtin_amdgcn_mfma_f32_16x16x32_bf16(g0, b0, d, 0, 0, 0);
    d = __builtin_amdgcn_mfma_f32_16x16x32_bf16(g1, b1, d, 0, 0, 0);
#pragma unroll
    for (int r2 = 0; r2 < 4; ++r2) {
      int t = mt * 16 + q * 4 + r2;
      int p = lt * 16 + i;
      float et = expf(cumS[t]);
      float xv = frombf(xp[(base + t) * 192 + p]);
      float y = d[r2] + et * dint[lt][r2] + Dv * xv;
      float zv = frombf(zp[(base + t) * 64 + p]);
      float v = y * siluf(zv);
      yv[lt][r2] = v;
      rowss[r2] += v * v;
    }
  }
#pragma unroll
  for (int m = 1; m < 16; m <<= 1) {
#pragma unroll
    for (int r2 = 0; r2 < 4; ++r2) rowss[r2] += __shfl_xor(rowss[r2], m);
  }
  float rscv[4];
#pragma unroll
  for (int r2 = 0; r2 < 4; ++r2)
    rscv[r2] = rsqrtf(rowss[r2] * (1.0f / 64.0f) + 1e-5f);
#pragma unroll
  for (int lt = 0; lt < 4; ++lt)
#pragma unroll
    for (int r2 = 0; r2 < 4; ++r2) {
      int t = mt * 16 + q * 4 + r2;
      int p = lt * 16 + i;
      Gb[t][p] = tobf(yv[lt][r2] * rscv[r2]);
    }
  __syncthreads();

  short8 y0 = *(const short8*)&Gb[mt * 16 + i][q * 8];
  short8 y1 = *(const short8*)&Gb[mt * 16 + i][q * 8 + 32];
  float* s2x = dir ? s2b : s2a;
#pragma unroll
  for (int dt = 0; dt < 2; ++dt) {
    short8 b0 = ldfrag(&WnT[dt * 16 + i][q * 8]);
    short8 b1 = ldfrag(&WnT[dt * 16 + i][q * 8 + 32]);
    f32x4 d = {0.f, 0.f, 0.f, 0.f};
    d = __builtin_amdgcn_mfma_f32_16x16x32_bf16(y0, b0, d, 0, 0, 0);
    d = __builtin_amdgcn_mfma_f32_16x16x32_bf16(y1, b1, d, 0, 0, 0);
#pragma unroll
    for (int r2 = 0; r2 < 4; ++r2) {
      int tl = mt * 16 + q * 4 + r2;
      int l = k * 64 + tl;
      int lout = dir ? (4095 - l) : l;
      int dd = dt * 16 + i;
      s2x[((long)b * 4096 + lout) * 32 + dd] = d[r2];
    }
  }
}

// K10: o3 = (s2a+s2b)@W — pure GEMM.
__global__ void k_fcout(const float* __restrict__ s2a, const float* __restrict__ s2b,
                        const float* __restrict__ w, float* __restrict__ o3) {
  __shared__ float st[32][68];
  __shared__ float wt[32][64];
  int b = blockIdx.y, l0 = blockIdx.x * 64, cb = blockIdx.z * 64;
  int tid = threadIdx.x;
  {
    int d = tid & 31, l = tid >> 5;
    for (int si = 0; si < 8; ++si) {
      int ll = l + si * 8;
      long o = ((long)b * 4096 + l0 + ll) * 32 + d;
      st[d][ll] = s2a[o] + s2b[o];
    }
    int f4 = (tid & 15) * 4, r = tid >> 4;
    for (int si = 0; si < 2; ++si) {
      int rr = r + si * 16;
      *(float4*)&wt[rr][f4] = *(const float4*)&w[rr * 128 + cb + f4];
    }
  }
  __syncthreads();
  int tx = tid & 15, ty = tid >> 4;
  int c0 = tx * 4, t0 = ty * 4;
  float acc[4][4] = {};
  for (int k = 0; k < 32; ++k) {
    float4 xv = *(float4*)&st[k][c0];
    float4 wv = *(float4*)&wt[k][t0];
    float xa[4] = {xv.x, xv.y, xv.z, xv.w};
    float wa[4] = {wv.x, wv.y, wv.z, wv.w};
#pragma unroll
    for (int a = 0; a < 4; ++a)
#pragma unroll
      for (int q = 0; q < 4; ++q) acc[a][q] += wa[a] * xa[q];
  }
#pragma unroll
  for (int a = 0; a < 4; ++a)
    *(float4*)&o3[((long)b * 128 + cb + t0 + a) * 4096 + l0 + c0] =
        make_float4(acc[a][0], acc[a][1], acc[a][2], acc[a][3]);
}

// K10b: per-channel sums for BatchNorm (2 atomics per block)
__global__ void k_bnstat(const float* __restrict__ o3, float* __restrict__ stats) {
  int bc = blockIdx.x;  // 1024 = (b,c)
  int tid = threadIdx.x;
  const float* p = o3 + (long)bc * 4096;
  float s = 0.f, q = 0.f;
  for (int i = tid * 4; i < 4096; i += 1024) {
    float4 v = *(const float4*)&p[i];
    s += v.x + v.y + v.z + v.w;
    q += v.x * v.x + v.y * v.y + v.z * v.z + v.w * v.w;
  }
  __shared__ float rs[4], rq[4];
  for (int off = 32; off; off >>= 1) { s += __shfl_down(s, off); q += __shfl_down(q, off); }
  if ((tid & 63) == 0) { rs[tid >> 6] = s; rq[tid >> 6] = q; }
  __syncthreads();
  if (tid == 0) {
    float a = rs[0] + rs[1] + rs[2] + rs[3];
    float b2 = rq[0] + rq[1] + rq[2] + rq[3];
    int c = bc & 127;
    atomicAdd(&stats[c], a);
    atomicAdd(&stats[128 + c], b2);
  }
}

// K12: BN + conv4 + sigmoid + gated residual — MFMA bf16 (BN folded in staging).
__global__ __launch_bounds__(256) void k_final(const float* __restrict__ o3,
                                               const float* __restrict__ stats,
                                               const float* __restrict__ bng,
                                               const float* __restrict__ bnb,
                                               const float* __restrict__ w,
                                               const float* __restrict__ bias,
                                               const float* __restrict__ x,
                                               float* __restrict__ out) {
  __shared__ unsigned short wT[64][140];
  __shared__ unsigned short aT[64][140];
  __shared__ float sc[128], sh[128];
  int b = blockIdx.y, l0 = blockIdx.x * 64, cb = blockIdx.z * 64;
  int tid = threadIdx.x, lane = tid & 63, mt = tid >> 6;
  int q = lane >> 4, i = lane & 15;
  if (tid < 128) {
    float mu = stats[tid] * (1.0f / 32768.0f);
    float var = stats[128 + tid] * (1.0f / 32768.0f) - mu * mu;
    float r = rsqrtf(var + 1e-5f);
    sc[tid] = r * bng[tid];
    sh[tid] = bnb[tid] - mu * r * bng[tid];
  }
  __syncthreads();
  int c4 = (tid & 15) * 4, k0 = tid >> 4;
#pragma unroll
  for (int s = 0; s < 8; ++s) {
    int k = k0 + s * 16;
    float4 wv = *(const float4*)&w[k * 128 + cb + c4];
    wT[c4 + 0][k] = tobf(wv.x); wT[c4 + 1][k] = tobf(wv.y);
    wT[c4 + 2][k] = tobf(wv.z); wT[c4 + 3][k] = tobf(wv.w);
    float4 av = *(const float4*)&o3[((long)b * 128 + k) * 4096 + l0 + c4];
    float scr = sc[k], shr = sh[k];
    aT[c4 + 0][k] = tobf(fmaf(av.x, scr, shr));
    aT[c4 + 1][k] = tobf(fmaf(av.y, scr, shr));
    aT[c4 + 2][k] = tobf(fmaf(av.z, scr, shr));
    aT[c4 + 3][k] = tobf(fmaf(av.w, scr, shr));
  }
  __syncthreads();
  short8 af[4];
#pragma unroll
  for (int kk = 0; kk < 4; ++kk)
    af[kk] = ldfrag(&wT[mt * 16 + i][q * 8 + 32 * kk]);
  float bv[4];
#pragma unroll
  for (int r2 = 0; r2 < 4; ++r2) bv[r2] = bias[cb + 16 * mt + q * 4 + r2];
#pragma unroll
  for (int nt = 0; nt < 4; ++nt) {
    f32x4 d = {0.f, 0.f, 0.f, 0.f};
#pragma unroll
    for (int kk = 0; kk < 4; ++kk) {
      short8 bfr = ldfrag(&aT[nt * 16 + i][q * 8 + 32 * kk]);
      d = __builtin_amdgcn_mfma_f32_16x16x32_bf16(af[kk], bfr, d, 0, 0, 0);
    }
#pragma unroll
    for (int r2 = 0; r2 < 4; ++r2) {
      int c = 16 * mt + q * 4 + r2;
      long xi = ((long)b * 128 + cb + c) * 4096 + l0 + nt * 16 + i;
      float g = 1.0f / (1.0f + expf(-(d[r2] + bv[r2])));
      out[xi] = x[xi] * (1.0f + g);
    }
  }
}

extern "C" void kernel_launch(void* const* d_in, const int* in_sizes, int n_in,
                              void* d_out, int out_size, void* d_ws, size_t ws_size,
                              hipStream_t stream) {
  const float* x          = (const float*)d_in[0];
  const float* lin1_w     = (const float*)d_in[1];
  const float* lin1_b     = (const float*)d_in[2];
  const float* dw_w       = (const float*)d_in[3];
  const float* dw_b       = (const float*)d_in[4];
  const float* fc_in_w    = (const float*)d_in[5];
  const float* mam_in_w   = (const float*)d_in[6];
  const float* mam_conv_w = (const float*)d_in[7];
  const float* mam_conv_b = (const float*)d_in[8];
  const float* mam_dt_bias= (const float*)d_in[9];
  const float* mam_A_log  = (const float*)d_in[10];
  const float* mam_D      = (const float*)d_in[11];
  const float* mam_norm_w = (const float*)d_in[12];
  const float* mam_out_w  = (const float*)d_in[13];
  const float* fc_out_w   = (const float*)d_in[14];
  const float* bn_g       = (const float*)d_in[15];
  const float* bn_b       = (const float*)d_in[16];
  const float* conv4_w    = (const float*)d_in[17];
  const float* conv4_b    = (const float*)d_in[18];
  float* out = (float*)d_out;
  float* ws  = (float*)d_ws;

  float* o1   = ws + OFF_O1;
  float* o2   = ws + OFF_O2;
  float* sbuf = ws + OFF_S;
  unsigned short* zbuf = (unsigned short*)(ws + OFF_Z);
  unsigned short* xbca = (unsigned short*)(ws + OFF_XBCA);
  float* dts  = ws + OFF_DTS;
  float* cum  = ws + OFF_CUM;
  float* Tbuf = ws + OFF_T;
  float* Sprev= ws + OFF_SPREV;
  float* s2a  = ws + OFF_S2A;
  float* s2b  = ws + OFF_S2B;
  float* bnst = ws + OFF_BN;
  float* o3   = ws + OFF_O3;

  hipMemsetAsync(bnst, 0, 256 * sizeof(float), stream);

  k_lin1<<<dim3(64, 8, 2), 256, 0, stream>>>(x, lin1_w, lin1_b, o1);
  k_dw<<<1024, 256, 0, stream>>>(o1, dw_w, dw_b, o2);
  k_fcin<<<dim3(64, 8), 256, 0, stream>>>(o2, fc_in_w, sbuf);
  k_inprojconv<<<dim3(64, 8, 2), 256, 0, stream>>>(sbuf, mam_in_w, mam_conv_w, mam_conv_b,
                                                   mam_dt_bias, mam_A_log,
                                                   zbuf, xbca, dts, cum);
  k_chunkT<<<dim3(512, 2), 256, 0, stream>>>(xbca, dts, cum, Tbuf);
  k_scan<<<256, 256, 0, stream>>>(Tbuf, cum, Sprev);
  k_chunkYout<<<dim3(512, 2), 256, 0, stream>>>(xbca, dts, cum, Sprev, mam_D, zbuf,
                                                mam_norm_w, mam_out_w, s2a, s2b);
  k_fcout<<<dim3(64, 8, 2), 256, 0, stream>>>(s2a, s2b, fc_out_w, o3);
  k_bnstat<<<1024, 256, 0, stream>>>(o3, bnst);
  k_final<<<dim3(64, 8, 2), 256, 0, stream>>>(o3, bnst, bn_g, bn_b, conv4_w, conv4_b, x, out);
}